// Round 2
// baseline (1165.283 us; speedup 1.0000x reference)
//
#include <hip/hip_runtime.h>
#include <hip/hip_bf16.h>

typedef __attribute__((ext_vector_type(4))) float f32x4;
typedef __attribute__((ext_vector_type(8))) short s16x8;

#define BSZ 128
#define TGT 197
#define EDIM 768
#define NH 12
#define HD 64
#define NF 16
#define M_TOT (BSZ*TGT)      // 25216
#define QKV_N (3*EDIM)       // 2304
#define KG (NF*TGT)          // 3152
#define KGP 3328             // KG padded to multiple of 256

__device__ __forceinline__ float b2f(unsigned short u) {
  return __uint_as_float(((unsigned int)u) << 16);
}
__device__ __forceinline__ float bf2f(__hip_bfloat16 b) { return __bfloat162float(b); }
__device__ __forceinline__ __hip_bfloat16 f2bf(float f) { return __float2bfloat16(f); }

__device__ __forceinline__ void gload_lds16(const void* gsrc, void* ldst) {
  __builtin_amdgcn_global_load_lds(
      (const __attribute__((address_space(1))) unsigned int*)gsrc,
      (__attribute__((address_space(3))) unsigned int*)ldst, 16, 0, 0);
}

// ---------------- dtype detection: 1 = bf16 storage, 0 = f32 storage ----------------
__global__ void detect_dtype(const unsigned short* __restrict__ xraw, int* __restrict__ flag) {
  if (threadIdx.x == 0 && blockIdx.x == 0) {
    float mx = 0.f;
    for (int j = 0; j < 1024; ++j) {
      float v = fabsf(b2f(xraw[j]));
      if (v < 1e30f) mx = fmaxf(mx, v);   // skip NaN/inf garbage cleanly
      else mx = 1e30f;
    }
    *flag = (mx < 100.0f) ? 1 : 0;
  }
}

// ---------------- canonicalize any float tensor to bf16 ----------------
__global__ __launch_bounds__(256) void convert_bf16(
    const void* __restrict__ src, __hip_bfloat16* __restrict__ dst,
    int n8, const int* __restrict__ flag)
{
  const int isbf = *flag;
  int i = blockIdx.x * 256 + threadIdx.x;
  const int stride = gridDim.x * 256;
  if (isbf) {
    const s16x8* s = (const s16x8*)src;
    s16x8* d = (s16x8*)dst;
    for (; i < n8; i += stride) d[i] = s[i];
  } else {
    const f32x4* s = (const f32x4*)src;
    s16x8* d = (s16x8*)dst;
    for (; i < n8; i += stride) {
      f32x4 a = s[i*2], b = s[i*2+1];
      s16x8 o;
      #pragma unroll
      for (int j = 0; j < 4; ++j) { __hip_bfloat16 t = f2bf(a[j]); o[j] = *(short*)&t; }
      #pragma unroll
      for (int j = 0; j < 4; ++j) { __hip_bfloat16 t = f2bf(b[j]); o[4+j] = *(short*)&t; }
      d[i] = o;
    }
  }
}

// ---------------- Wc = in_proj_weight + lora_b @ lora_a ----------------
__global__ __launch_bounds__(256) void build_wc(
    const __hip_bfloat16* __restrict__ W,
    const __hip_bfloat16* __restrict__ la,   // [64][768]
    const __hip_bfloat16* __restrict__ lb,   // [2304][64]
    __hip_bfloat16* __restrict__ Wc)
{
  __shared__ float lbr[64];
  const int n = blockIdx.x;
  if (threadIdx.x < 64) lbr[threadIdx.x] = bf2f(lb[n*64 + threadIdx.x]);
  __syncthreads();
  for (int e = threadIdx.x; e < EDIM; e += 256) {
    float acc = bf2f(W[(size_t)n*EDIM + e]);
    for (int r = 0; r < 64; ++r) acc += lbr[r] * bf2f(la[r*EDIM + e]);
    Wc[(size_t)n*EDIM + e] = f2bf(acc);
  }
}

// ---------------- GEMM: C[M][N] = A[M][K] @ B[N][K]^T + bias ----------------
// M%128==0, N%128==0, K%32==0. 4 waves, 128x128 tile, 16 KB LDS.
// flag_mode: 0 -> always store bf16 (internal); 1 -> store f32 iff *flag==0.
__global__ __launch_bounds__(256) void gemm_bt_bias(
    const __hip_bfloat16* __restrict__ A,
    const __hip_bfloat16* __restrict__ B,
    const __hip_bfloat16* __restrict__ bias,
    void* __restrict__ C,
    int M, int N, int K, const int* __restrict__ flag, int flag_mode)
{
  __shared__ __hip_bfloat16 lA[128*32];
  __shared__ __hip_bfloat16 lB[128*32];
  const int tid = threadIdx.x;
  const int wave = tid >> 6, lane = tid & 63;
  const int l16 = lane & 15, kq = lane >> 4;
  const long brow = (long)blockIdx.x * 128;
  const long bcol = (long)blockIdx.y * 128;
  const int wr = (wave >> 1) * 64;
  const int wc = (wave & 1) * 64;
  const int sr = tid >> 2;
  const int sc = (tid & 3) * 8;
  const int f32o = flag_mode && (*flag == 0);

  f32x4 acc[4][4];
  #pragma unroll
  for (int i = 0; i < 4; i++)
    #pragma unroll
    for (int j = 0; j < 4; j++) acc[i][j] = (f32x4){0.f,0.f,0.f,0.f};

  char* lAb = (char*)lA;
  char* lBb = (char*)lB;
  const int wbase = wave * 1024;

  for (int k0 = 0; k0 < K; k0 += 32) {
    __syncthreads();
    gload_lds16(A + (brow + sr)      * (long)K + k0 + sc, lAb + wbase);
    gload_lds16(A + (brow + sr + 64) * (long)K + k0 + sc, lAb + 4096 + wbase);
    gload_lds16(B + (bcol + sr)      * (long)K + k0 + sc, lBb + wbase);
    gload_lds16(B + (bcol + sr + 64) * (long)K + k0 + sc, lBb + 4096 + wbase);
    __syncthreads();
    s16x8 af[4], bfr[4];
    #pragma unroll
    for (int mi = 0; mi < 4; mi++)
      af[mi] = *(const s16x8*)(lAb + ((wr + mi*16 + l16)*32 + kq*8)*2);
    #pragma unroll
    for (int ni = 0; ni < 4; ni++)
      bfr[ni] = *(const s16x8*)(lBb + ((wc + ni*16 + l16)*32 + kq*8)*2);
    #pragma unroll
    for (int mi = 0; mi < 4; mi++)
      #pragma unroll
      for (int ni = 0; ni < 4; ni++)
        acc[mi][ni] = __builtin_amdgcn_mfma_f32_16x16x32_bf16(af[mi], bfr[ni], acc[mi][ni], 0, 0, 0);
  }

  const int o4 = (lane >> 4) * 4;
  #pragma unroll
  for (int ni = 0; ni < 4; ni++) {
    const long col = bcol + wc + ni*16 + l16;
    const float bv = bf2f(bias[col]);
    #pragma unroll
    for (int mi = 0; mi < 4; mi++) {
      #pragma unroll
      for (int r = 0; r < 4; r++) {
        const long row = brow + wr + mi*16 + o4 + r;
        const float val = acc[mi][ni][r] + bv;
        if (f32o) ((float*)C)[row * (long)N + col] = val;
        else ((__hip_bfloat16*)C)[row * (long)N + col] = f2bf(val);
      }
    }
  }
}

// ---------------- fused attention per (i,h,qtile of 64) ----------------
// LDS: lKV[224*64] (K, then reused as V^T[64][224]) + lS[64*224] + lRS = 57.6 KB
__global__ __launch_bounds__(256) void attn_fused(
    const __hip_bfloat16* __restrict__ qkv,   // [M_TOT][2304]
    const __hip_bfloat16* __restrict__ mask,  // [BSZ][TGT][TGT]
    __hip_bfloat16* __restrict__ xop)         // [M_TOT][768]
{
  __shared__ __hip_bfloat16 lKV[224*64];
  __shared__ __hip_bfloat16 lS[64*224];
  __shared__ float lRS[64];

  const int tid = threadIdx.x;
  const int blk = blockIdx.x;
  const int qt = blk & 3;
  const int ih = blk >> 2;
  const int h = ih % NH;
  const int i = ih / NH;
  const int q0 = qt * 64;
  const size_t rowbase = (size_t)i * TGT;
  const int wave = tid >> 6, lane = tid & 63;
  const int l16 = lane & 15, kq = lane >> 4, o4 = (lane >> 4) * 4;

  // stage K [224][64] (zero-padded rows >= TGT)
  const f32x4 z = {0.f,0.f,0.f,0.f};
  for (int idx = tid; idx < 224*8; idx += 256) {
    int t = idx >> 3, c8 = idx & 7;
    f32x4 v = z;
    if (t < TGT) v = *(const f32x4*)(qkv + (rowbase + t)*QKV_N + EDIM + h*HD + c8*8);
    *(f32x4*)(lKV + t*64 + c8*8) = v;
  }

  // Q fragments straight from global (row-clamped; padded rows discarded later)
  int qrl = q0 + wave*16 + l16; if (qrl > TGT-1) qrl = TGT-1;
  s16x8 qf[2];
  #pragma unroll
  for (int kk = 0; kk < 2; ++kk)
    qf[kk] = *(const s16x8*)(qkv + (rowbase + qrl)*QKV_N + h*HD + kk*32 + kq*8);
  __syncthreads();

  // S = (Q K^T)*scale + mask  -> lS rows 0..63
  for (int nf = 0; nf < 14; ++nf) {
    f32x4 a = {0.f,0.f,0.f,0.f};
    #pragma unroll
    for (int kk = 0; kk < 2; ++kk) {
      s16x8 kf = *(const s16x8*)(lKV + (nf*16 + l16)*64 + kk*32 + kq*8);
      a = __builtin_amdgcn_mfma_f32_16x16x32_bf16(qf[kk], kf, a, 0, 0, 0);
    }
    const int col = nf*16 + l16;
    #pragma unroll
    for (int r = 0; r < 4; ++r) {
      float sv = a[r] * 0.125f;
      const int qrow = q0 + wave*16 + o4 + r;
      if (qrow < TGT && col < TGT) sv += bf2f(mask[(rowbase + qrow)*TGT + col]);
      lS[(wave*16 + o4 + r)*224 + col] = f2bf(sv);
    }
  }
  __syncthreads();

  // softmax per row: store unnormalized exp, keep rowsum
  if (tid < 64) {
    float mx = -1e30f;
    for (int c = 0; c < TGT; ++c) mx = fmaxf(mx, bf2f(lS[tid*224 + c]));
    float sum = 0.f;
    for (int c = 0; c < 224; ++c) {
      float e = 0.f;
      if (c < TGT) { e = __expf(bf2f(lS[tid*224 + c]) - mx); sum += e; }
      lS[tid*224 + c] = f2bf(e);
    }
    lRS[tid] = sum;
  }
  __syncthreads();

  // stage V^T [64][224] into lKV (K no longer needed)
  for (int idx = tid; idx < 224*8; idx += 256) {
    int t = idx >> 3, c8 = idx & 7;
    if (t < TGT) {
      f32x4 v = *(const f32x4*)(qkv + (rowbase + t)*QKV_N + 2*EDIM + h*HD + c8*8);
      const __hip_bfloat16* pv = (const __hip_bfloat16*)&v;
      #pragma unroll
      for (int j = 0; j < 8; ++j) lKV[(c8*8+j)*224 + t] = pv[j];
    } else {
      #pragma unroll
      for (int j = 0; j < 8; ++j) lKV[(c8*8+j)*224 + t] = f2bf(0.f);
    }
  }
  __syncthreads();

  // O = P V  (K-dim 224, zero-padded)
  f32x4 oacc[4];
  #pragma unroll
  for (int nf = 0; nf < 4; ++nf) oacc[nf] = (f32x4){0.f,0.f,0.f,0.f};
  for (int kt = 0; kt < 7; ++kt) {
    s16x8 pa = *(const s16x8*)(lS + (wave*16 + l16)*224 + kt*32 + kq*8);
    #pragma unroll
    for (int nf = 0; nf < 4; ++nf) {
      s16x8 vb = *(const s16x8*)(lKV + (nf*16 + l16)*224 + kt*32 + kq*8);
      oacc[nf] = __builtin_amdgcn_mfma_f32_16x16x32_bf16(pa, vb, oacc[nf], 0, 0, 0);
    }
  }
  #pragma unroll
  for (int r = 0; r < 4; ++r) {
    const int qrow = q0 + wave*16 + o4 + r;
    if (qrow < TGT) {
      const float inv = 1.0f / lRS[wave*16 + o4 + r];
      #pragma unroll
      for (int nf = 0; nf < 4; ++nf)
        xop[(rowbase + qrow)*(size_t)EDIM + h*HD + nf*16 + l16] =
            f2bf(oacc[nf][r] * inv);
    }
  }
}

// ---------------- CLS grouped attention, S kept in global ws ----------------
// per (g,h): 16 queries x 3152 keys. LDS 36 KB.
__global__ __launch_bounds__(256) void cls_attn(
    const __hip_bfloat16* __restrict__ qkv,
    const __hip_bfloat16* __restrict__ mask,
    const int* __restrict__ top_idx,
    __hip_bfloat16* __restrict__ Sg_all,      // [96][16][KGP]
    __hip_bfloat16* __restrict__ x1buf)       // [BSZ][768]
{
  __shared__ __hip_bfloat16 lQ[16*64];
  __shared__ __hip_bfloat16 lVt[64*256];
  __shared__ float red[16][17];
  __shared__ float rmax[16];
  __shared__ float rsum[16];

  const int tid = threadIdx.x;
  const int g = blockIdx.x / NH;
  const int h = blockIdx.x % NH;
  __hip_bfloat16* Sg = Sg_all + (size_t)blockIdx.x * 16 * KGP;
  const int wave = tid >> 6, lane = tid & 63;
  const int l16 = lane & 15, kq = lane >> 4, o4 = (lane >> 4) * 4;

  // stage q_1
  if (tid < 128) {
    int qi = tid >> 3, c8 = tid & 7;
    int ib = g*NF + qi;
    int top = top_idx[ib];
    f32x4 v = *(const f32x4*)(qkv + ((size_t)ib*TGT + top)*QKV_N + h*HD + c8*8);
    *(f32x4*)(lQ + qi*64 + c8*8) = v;
  }
  __syncthreads();

  s16x8 q8[2];
  #pragma unroll
  for (int kk = 0; kk < 2; ++kk)
    q8[kk] = *(const s16x8*)(lQ + l16*64 + kk*32 + kq*8);

  // S1 = q1 Kg^T * scale + mask_g  (208 col-tiles incl. zero pad)
  for (int nf = wave; nf < 208; nf += 4) {
    const int key = nf*16 + l16;
    if (nf < 197) {
      f32x4 a = {0.f,0.f,0.f,0.f};
      const size_t krow = (size_t)g*KG + key;
      #pragma unroll
      for (int kk = 0; kk < 2; ++kk) {
        s16x8 k8 = *(const s16x8*)(qkv + krow*QKV_N + EDIM + h*HD + kk*32 + kq*8);
        a = __builtin_amdgcn_mfma_f32_16x16x32_bf16(q8[kk], k8, a, 0, 0, 0);
      }
      const int f = key / 197;
      const int t = key - f*197;
      const float mval = bf2f(mask[((size_t)(g*NF + f)*TGT + (TGT-1))*TGT + t]);
      #pragma unroll
      for (int r = 0; r < 4; ++r)
        Sg[(o4 + r)*KGP + key] = f2bf(a[r]*0.125f + mval);
    } else {
      #pragma unroll
      for (int r = 0; r < 4; ++r)
        Sg[(o4 + r)*KGP + key] = f2bf(0.f);   // pad: P stays 0
    }
  }
  __syncthreads();

  // softmax over 3152 cols; 16 threads per row; exp values written back
  {
    const int q = tid >> 4, c = tid & 15;
    float mx = -1e30f;
    for (int kk = c; kk < KG; kk += 16)
      mx = fmaxf(mx, bf2f(Sg[q*KGP + kk]));
    red[q][c] = mx;
    __syncthreads();
    if (tid < 16) {
      float m = red[tid][0];
      for (int j = 1; j < 16; ++j) m = fmaxf(m, red[tid][j]);
      rmax[tid] = m;
    }
    __syncthreads();
    const float rowmax = rmax[q];
    float sum = 0.f;
    for (int kk = c; kk < KG; kk += 16) {
      float e = __expf(bf2f(Sg[q*KGP + kk]) - rowmax);
      Sg[q*KGP + kk] = f2bf(e);
      sum += e;
    }
    red[q][c] = sum;
    __syncthreads();
    if (tid < 16) {
      float s = 0.f;
      for (int j = 0; j < 16; ++j) s += red[tid][j];
      rsum[tid] = s;
    }
  }

  // PV over chunks of 256 keys; wave w owns output cols w*16..w*16+15
  f32x4 oa = {0.f,0.f,0.f,0.f};
  for (int ck = 0; ck < KGP; ck += 256) {
    __syncthreads();
    for (int idx = tid; idx < 256*8; idx += 256) {
      int j = idx >> 3, c8 = idx & 7;
      int key = ck + j;
      if (key < KG) {
        f32x4 v = *(const f32x4*)(qkv + ((size_t)g*KG + key)*QKV_N + 2*EDIM + h*HD + c8*8);
        const __hip_bfloat16* pv = (const __hip_bfloat16*)&v;
        #pragma unroll
        for (int jj = 0; jj < 8; ++jj) lVt[(c8*8+jj)*256 + j] = pv[jj];
      } else {
        #pragma unroll
        for (int jj = 0; jj < 8; ++jj) lVt[(c8*8+jj)*256 + j] = f2bf(0.f);
      }
    }
    __syncthreads();
    #pragma unroll
    for (int ks = 0; ks < 8; ++ks) {
      s16x8 pa = *(const s16x8*)(Sg + l16*KGP + ck + ks*32 + kq*8);
      s16x8 vb = *(const s16x8*)(lVt + (wave*16 + l16)*256 + ks*32 + kq*8);
      oa = __builtin_amdgcn_mfma_f32_16x16x32_bf16(pa, vb, oa, 0, 0, 0);
    }
  }
  #pragma unroll
  for (int r = 0; r < 4; ++r) {
    int q = o4 + r;
    int ib = g*NF + q;
    x1buf[(size_t)ib*EDIM + h*HD + wave*16 + l16] = f2bf(oa[r] / rsum[q]);
  }
}

// ---------------- LoRA head + CLS row update (flag-aware d_out access) ----------------
__global__ __launch_bounds__(256) void final_update(
    void* __restrict__ out,
    const __hip_bfloat16* __restrict__ x1p,   // [BSZ][768]
    const __hip_bfloat16* __restrict__ dw, const __hip_bfloat16* __restrict__ db,
    const __hip_bfloat16* __restrict__ uw, const __hip_bfloat16* __restrict__ ub,
    const int* __restrict__ top_idx, const int* __restrict__ flag)
{
  __shared__ float x0[EDIM];
  __shared__ float hmid[64];
  const int i = blockIdx.x;
  const int tid = threadIdx.x;
  const int top = top_idx[i];
  const int isbf = *flag;
  const size_t rowoff = ((size_t)i*TGT + top)*EDIM;
  for (int e = tid; e < EDIM; e += 256)
    x0[e] = isbf ? bf2f(((const __hip_bfloat16*)out)[rowoff + e])
                 : ((const float*)out)[rowoff + e];
  __syncthreads();
  if (tid < 64) {
    float a = bf2f(db[tid]);
    for (int e = 0; e < EDIM; ++e) a += x0[e] * bf2f(dw[tid*EDIM + e]);
    hmid[tid] = a / (1.f + __expf(-1.702f * a));   // quick_gelu
  }
  __syncthreads();
  for (int e = tid; e < EDIM; e += 256) {
    float a = bf2f(ub[e]) + bf2f(x1p[(size_t)i*EDIM + e]);
    #pragma unroll
    for (int r = 0; r < 64; ++r) a += hmid[r] * bf2f(uw[e*64 + r]);
    if (isbf) ((__hip_bfloat16*)out)[rowoff + e] = f2bf(a);
    else ((float*)out)[rowoff + e] = a;
  }
}

extern "C" void kernel_launch(void* const* d_in, const int* in_sizes, int n_in,
                              void* d_out, int out_size, void* d_ws, size_t ws_size,
                              hipStream_t stream) {
  (void)in_sizes; (void)n_in; (void)out_size; (void)ws_size;
  const int* top_idx = (const int*)d_in[13];

  char* ws = (char*)d_ws;
  size_t off = 0;
  auto alloc = [&](size_t bytes) { char* p = ws + off; off += (bytes + 15) & ~(size_t)15; return p; };

  int* flag = (int*)alloc(16);
  __hip_bfloat16* x_c    = (__hip_bfloat16*)alloc((size_t)19365888*2);
  __hip_bfloat16* mask_c = (__hip_bfloat16*)alloc((size_t)4967552*2);
  __hip_bfloat16* wIn_c  = (__hip_bfloat16*)alloc((size_t)1769472*2);
  __hip_bfloat16* bIn_c  = (__hip_bfloat16*)alloc((size_t)2304*2);
  __hip_bfloat16* wOut_c = (__hip_bfloat16*)alloc((size_t)589824*2);
  __hip_bfloat16* bOut_c = (__hip_bfloat16*)alloc((size_t)768*2);
  __hip_bfloat16* la_c   = (__hip_bfloat16*)alloc((size_t)49152*2);
  __hip_bfloat16* lb_c   = (__hip_bfloat16*)alloc((size_t)147456*2);
  __hip_bfloat16* dw_c   = (__hip_bfloat16*)alloc((size_t)49152*2);
  __hip_bfloat16* db_c   = (__hip_bfloat16*)alloc((size_t)64*2);
  __hip_bfloat16* uw_c   = (__hip_bfloat16*)alloc((size_t)49152*2);
  __hip_bfloat16* ub_c   = (__hip_bfloat16*)alloc((size_t)768*2);
  __hip_bfloat16* Wc     = (__hip_bfloat16*)alloc((size_t)QKV_N*EDIM*2);
  __hip_bfloat16* qkv    = (__hip_bfloat16*)alloc((size_t)M_TOT*QKV_N*2);
  __hip_bfloat16* xop    = (__hip_bfloat16*)alloc((size_t)M_TOT*EDIM*2);
  __hip_bfloat16* x1b    = (__hip_bfloat16*)alloc((size_t)BSZ*EDIM*2);
  __hip_bfloat16* x1p    = (__hip_bfloat16*)alloc((size_t)BSZ*EDIM*2);
  __hip_bfloat16* Sg     = (__hip_bfloat16*)alloc((size_t)96*16*KGP*2);

  detect_dtype<<<1, 64, 0, stream>>>((const unsigned short*)d_in[0], flag);

  auto CV = [&](int idx, __hip_bfloat16* dst, int n) {
    int n8 = n / 8;
    int grid = (n8 + 255) / 256; if (grid > 2048) grid = 2048; if (grid < 1) grid = 1;
    convert_bf16<<<grid, 256, 0, stream>>>(d_in[idx], dst, n8, flag);
  };
  CV(0,  x_c,    19365888);
  CV(1,  mask_c, 4967552);
  CV(2,  wIn_c,  1769472);
  CV(3,  bIn_c,  2304);
  CV(4,  wOut_c, 589824);
  CV(5,  bOut_c, 768);
  CV(6,  la_c,   49152);
  CV(7,  lb_c,   147456);
  CV(8,  dw_c,   49152);
  CV(9,  db_c,   64);
  CV(10, uw_c,   49152);
  CV(11, ub_c,   768);

  build_wc<<<2304, 256, 0, stream>>>(wIn_c, la_c, lb_c, Wc);
  gemm_bt_bias<<<dim3(197, 18), 256, 0, stream>>>(x_c, Wc, bIn_c, qkv, M_TOT, QKV_N, EDIM, flag, 0);
  attn_fused<<<dim3(6144), 256, 0, stream>>>(qkv, mask_c, xop);
  gemm_bt_bias<<<dim3(197, 6), 256, 0, stream>>>(xop, wOut_c, bOut_c, d_out, M_TOT, EDIM, EDIM, flag, 1);
  cls_attn<<<dim3(96), 256, 0, stream>>>(qkv, mask_c, top_idx, Sg, x1b);
  gemm_bt_bias<<<dim3(1, 6), 256, 0, stream>>>(x1b, wOut_c, bOut_c, x1p, BSZ, EDIM, EDIM, flag, 0);
  final_update<<<128, 256, 0, stream>>>(d_out, x1p, dw_c, db_c, uw_c, ub_c, top_idx, flag);
}

// Round 3
// 729.473 us; speedup vs baseline: 1.5974x; 1.5974x over previous
//
#include <hip/hip_runtime.h>
#include <hip/hip_bf16.h>

typedef __attribute__((ext_vector_type(4))) float f32x4;
typedef __attribute__((ext_vector_type(8))) short s16x8;

#define BSZ 128
#define TGT 197
#define EDIM 768
#define NH 12
#define HD 64
#define NF 16
#define M_TOT (BSZ*TGT)      // 25216
#define QKV_N (3*EDIM)       // 2304
#define KG (NF*TGT)          // 3152
#define KGP 3328             // KG padded to multiple of 256

__device__ __forceinline__ float b2f(unsigned short u) {
  return __uint_as_float(((unsigned int)u) << 16);
}
__device__ __forceinline__ float bf2f(__hip_bfloat16 b) { return __bfloat162float(b); }
__device__ __forceinline__ __hip_bfloat16 f2bf(float f) { return __float2bfloat16(f); }
__device__ __forceinline__ unsigned int packbf(float a, float b) {
  __hip_bfloat16 x = __float2bfloat16(a), y = __float2bfloat16(b);
  return (unsigned int)*(unsigned short*)&x | ((unsigned int)*(unsigned short*)&y << 16);
}
// swizzled short-index into a [T][64] bf16 LDS tile; keeps 16B alignment,
// spreads banks for both row-wise b128 reads (t&7 term) and column-wise
// scalar gathers at t-stride 8 (t>>3 term).
__device__ __forceinline__ int swz(int t, int c) {
  return t*64 + (c ^ ((((t & 7) ^ ((t >> 3) & 3))) << 3));
}

__device__ __forceinline__ void gload_lds16(const void* gsrc, void* ldst) {
  __builtin_amdgcn_global_load_lds(
      (const __attribute__((address_space(1))) unsigned int*)gsrc,
      (__attribute__((address_space(3))) unsigned int*)ldst, 16, 0, 0);
}

// ---------------- dtype detection: 1 = bf16 storage, 0 = f32 storage ----------------
__global__ void detect_dtype(const unsigned short* __restrict__ xraw, int* __restrict__ flag) {
  if (threadIdx.x == 0 && blockIdx.x == 0) {
    float mx = 0.f;
    for (int j = 0; j < 1024; ++j) {
      float v = fabsf(b2f(xraw[j]));
      if (v < 1e30f) mx = fmaxf(mx, v);
      else mx = 1e30f;
    }
    *flag = (mx < 100.0f) ? 1 : 0;
  }
}

// ---------------- canonicalize any float tensor to bf16 ----------------
__global__ __launch_bounds__(256) void convert_bf16(
    const void* __restrict__ src, __hip_bfloat16* __restrict__ dst,
    int n8, const int* __restrict__ flag)
{
  const int isbf = *flag;
  int i = blockIdx.x * 256 + threadIdx.x;
  const int stride = gridDim.x * 256;
  if (isbf) {
    const s16x8* s = (const s16x8*)src;
    s16x8* d = (s16x8*)dst;
    for (; i < n8; i += stride) d[i] = s[i];
  } else {
    const f32x4* s = (const f32x4*)src;
    s16x8* d = (s16x8*)dst;
    for (; i < n8; i += stride) {
      f32x4 a = s[i*2], b = s[i*2+1];
      s16x8 o;
      #pragma unroll
      for (int j = 0; j < 4; ++j) { __hip_bfloat16 t = f2bf(a[j]); o[j] = *(short*)&t; }
      #pragma unroll
      for (int j = 0; j < 4; ++j) { __hip_bfloat16 t = f2bf(b[j]); o[4+j] = *(short*)&t; }
      d[i] = o;
    }
  }
}

// ---------------- Wc = in_proj_weight + lora_b @ lora_a ----------------
__global__ __launch_bounds__(256) void build_wc(
    const __hip_bfloat16* __restrict__ W,
    const __hip_bfloat16* __restrict__ la,
    const __hip_bfloat16* __restrict__ lb,
    __hip_bfloat16* __restrict__ Wc)
{
  __shared__ float lbr[64];
  const int n = blockIdx.x;
  if (threadIdx.x < 64) lbr[threadIdx.x] = bf2f(lb[n*64 + threadIdx.x]);
  __syncthreads();
  for (int e = threadIdx.x; e < EDIM; e += 256) {
    float acc = bf2f(W[(size_t)n*EDIM + e]);
    for (int r = 0; r < 64; ++r) acc += lbr[r] * bf2f(la[r*EDIM + e]);
    Wc[(size_t)n*EDIM + e] = f2bf(acc);
  }
}

// ---------------- GEMM: C[M][N] = A[M][K] @ B[N][K]^T + bias ----------------
__global__ __launch_bounds__(256) void gemm_bt_bias(
    const __hip_bfloat16* __restrict__ A,
    const __hip_bfloat16* __restrict__ B,
    const __hip_bfloat16* __restrict__ bias,
    void* __restrict__ C,
    int M, int N, int K, const int* __restrict__ flag, int flag_mode)
{
  __shared__ __hip_bfloat16 lA[128*32];
  __shared__ __hip_bfloat16 lB[128*32];
  const int tid = threadIdx.x;
  const int wave = tid >> 6, lane = tid & 63;
  const int l16 = lane & 15, kq = lane >> 4;
  const long brow = (long)blockIdx.x * 128;
  const long bcol = (long)blockIdx.y * 128;
  const int wr = (wave >> 1) * 64;
  const int wc = (wave & 1) * 64;
  const int sr = tid >> 2;
  const int sc = (tid & 3) * 8;
  const int f32o = flag_mode && (*flag == 0);

  f32x4 acc[4][4];
  #pragma unroll
  for (int i = 0; i < 4; i++)
    #pragma unroll
    for (int j = 0; j < 4; j++) acc[i][j] = (f32x4){0.f,0.f,0.f,0.f};

  char* lAb = (char*)lA;
  char* lBb = (char*)lB;
  const int wbase = wave * 1024;

  for (int k0 = 0; k0 < K; k0 += 32) {
    __syncthreads();
    gload_lds16(A + (brow + sr)      * (long)K + k0 + sc, lAb + wbase);
    gload_lds16(A + (brow + sr + 64) * (long)K + k0 + sc, lAb + 4096 + wbase);
    gload_lds16(B + (bcol + sr)      * (long)K + k0 + sc, lBb + wbase);
    gload_lds16(B + (bcol + sr + 64) * (long)K + k0 + sc, lBb + 4096 + wbase);
    __syncthreads();
    s16x8 af[4], bfr[4];
    #pragma unroll
    for (int mi = 0; mi < 4; mi++)
      af[mi] = *(const s16x8*)(lAb + ((wr + mi*16 + l16)*32 + kq*8)*2);
    #pragma unroll
    for (int ni = 0; ni < 4; ni++)
      bfr[ni] = *(const s16x8*)(lBb + ((wc + ni*16 + l16)*32 + kq*8)*2);
    #pragma unroll
    for (int mi = 0; mi < 4; mi++)
      #pragma unroll
      for (int ni = 0; ni < 4; ni++)
        acc[mi][ni] = __builtin_amdgcn_mfma_f32_16x16x32_bf16(af[mi], bfr[ni], acc[mi][ni], 0, 0, 0);
  }

  const int o4 = (lane >> 4) * 4;
  #pragma unroll
  for (int ni = 0; ni < 4; ni++) {
    const long col = bcol + wc + ni*16 + l16;
    const float bv = bf2f(bias[col]);
    #pragma unroll
    for (int mi = 0; mi < 4; mi++) {
      #pragma unroll
      for (int r = 0; r < 4; r++) {
        const long row = brow + wr + mi*16 + o4 + r;
        const float val = acc[mi][ni][r] + bv;
        if (f32o) ((float*)C)[row * (long)N + col] = val;
        else ((__hip_bfloat16*)C)[row * (long)N + col] = f2bf(val);
      }
    }
  }
}

// ---------------- fused attention, swapped-QK^T in-register softmax ----------------
// block = (i,h,qt); LDS: lK[224][64] + lV[224][64] swizzled = 57.4 KB; ONE barrier.
__global__ __launch_bounds__(256) void attn_fused(
    const __hip_bfloat16* __restrict__ qkv,   // [M_TOT][2304]
    const __hip_bfloat16* __restrict__ mask,  // [BSZ][TGT][TGT]
    __hip_bfloat16* __restrict__ xop)         // [M_TOT][768]
{
  __shared__ __hip_bfloat16 lK[224*64];
  __shared__ __hip_bfloat16 lV[224*64];

  const int tid = threadIdx.x;
  // XCD-chunked mapping: all 4 q-tiles of an (i,h) on one XCD, contiguous ih per XCD
  const int blk = blockIdx.x;
  const int xcd = blk & 7;
  const int slot = blk >> 3;            // 0..767
  const int ih = xcd * 192 + (slot >> 2);
  const int qt = slot & 3;
  const int h = ih % NH;
  const int i = ih / NH;
  const int q0 = qt * 64;
  const size_t rowbase = (size_t)i * TGT;
  const int wave = tid >> 6, lane = tid & 63;
  const int l16 = lane & 15, kq = lane >> 4;

  // ---- stage K and V rows [224][64], swizzled, zero-padded ----
  const f32x4 z = {0.f,0.f,0.f,0.f};
  for (int idx = tid; idx < 224*8; idx += 256) {
    int t = idx >> 3, c8 = idx & 7;
    f32x4 kv = z, vv = z;
    if (t < TGT) {
      kv = *(const f32x4*)(qkv + (rowbase + t)*QKV_N + EDIM   + h*HD + c8*8);
      vv = *(const f32x4*)(qkv + (rowbase + t)*QKV_N + 2*EDIM + h*HD + c8*8);
    }
    *(f32x4*)(lK + swz(t, c8*8)) = kv;
    *(f32x4*)(lV + swz(t, c8*8)) = vv;
  }

  // ---- Q fragment (B-operand): lane n=l16 -> q row; straight from global ----
  int qr = q0 + wave*16 + l16;
  const int qrc = qr > TGT-1 ? TGT-1 : qr;
  s16x8 qf[2];
  #pragma unroll
  for (int kk = 0; kk < 2; ++kk)
    qf[kk] = *(const s16x8*)(qkv + (rowbase + qrc)*QKV_N + h*HD + kk*32 + kq*8);

  __syncthreads();   // the only barrier

  // ---- S^T = mfma(K, Q): lane holds S^T[t = nf*16 + kq*4 + r][q = l16-row] ----
  f32x4 acc[14];
  #pragma unroll
  for (int nf = 0; nf < 14; ++nf) {
    acc[nf] = (f32x4){0.f,0.f,0.f,0.f};
    #pragma unroll
    for (int kk = 0; kk < 2; ++kk) {
      s16x8 kf = *(const s16x8*)(lK + swz(nf*16 + l16, kk*32 + kq*8));
      acc[nf] = __builtin_amdgcn_mfma_f32_16x16x32_bf16(kf, qf[kk], acc[nf], 0, 0, 0);
    }
  }

  // ---- in-register softmax (4-lane group reduce over kq) ----
  float mx = -1e30f;
  #pragma unroll
  for (int nf = 0; nf < 14; ++nf) {
    #pragma unroll
    for (int r = 0; r < 4; ++r) {
      const int t = nf*16 + kq*4 + r;
      float s;
      if (t < TGT) s = acc[nf][r]*0.125f + bf2f(mask[(rowbase + qrc)*TGT + t]);
      else s = -1e30f;
      acc[nf][r] = s;
      mx = fmaxf(mx, s);
    }
  }
  mx = fmaxf(mx, __shfl_xor(mx, 16));
  mx = fmaxf(mx, __shfl_xor(mx, 32));

  float rs = 0.f;
  unsigned int pk[14][2];
  #pragma unroll
  for (int nf = 0; nf < 14; ++nf) {
    float p0 = __expf(acc[nf][0] - mx);
    float p1 = __expf(acc[nf][1] - mx);
    float p2 = __expf(acc[nf][2] - mx);
    float p3 = __expf(acc[nf][3] - mx);
    rs += (p0 + p1) + (p2 + p3);
    pk[nf][0] = packbf(p0, p1);
    pk[nf][1] = packbf(p2, p3);
  }
  rs += __shfl_xor(rs, 16);
  rs += __shfl_xor(rs, 32);

  // ---- O = P V: A-frag via cross-lane shuffle, B-frag via swizzled scalar gather ----
  f32x4 oacc[4];
  #pragma unroll
  for (int nf = 0; nf < 4; ++nf) oacc[nf] = (f32x4){0.f,0.f,0.f,0.f};

  const int slbase = l16 + ((kq & 1) << 5);
  #pragma unroll
  for (int kt = 0; kt < 7; ++kt) {
    s16x8 pa;
    #pragma unroll
    for (int jp = 0; jp < 4; ++jp) {
      const int srcLane = slbase + ((jp >> 1) << 4);
      int va = __shfl((int)pk[2*kt][jp & 1], srcLane, 64);
      int vb = __shfl((int)pk[2*kt + 1][jp & 1], srcLane, 64);
      int sel = (kq < 2) ? va : vb;
      pa[2*jp]     = (short)(sel & 0xffff);
      pa[2*jp + 1] = (short)(((unsigned int)sel) >> 16);
    }
    #pragma unroll
    for (int nf = 0; nf < 4; ++nf) {
      s16x8 vf;
      #pragma unroll
      for (int j = 0; j < 8; ++j) {
        const int t = kt*32 + kq*8 + j;
        vf[j] = *(const short*)(lV + swz(t, nf*16 + l16));
      }
      oacc[nf] = __builtin_amdgcn_mfma_f32_16x16x32_bf16(pa, vf, oacc[nf], 0, 0, 0);
    }
  }

  // ---- epilogue: C[m=q-within-16][n=d]; rowsum fetched from owning lane ----
  #pragma unroll
  for (int r = 0; r < 4; ++r) {
    const float rsrc = __shfl(rs, kq*4 + r, 64);
    const int qw = q0 + wave*16 + kq*4 + r;
    if (qw < TGT) {
      const float inv = 1.0f / rsrc;
      #pragma unroll
      for (int nf = 0; nf < 4; ++nf)
        xop[(rowbase + qw)*(size_t)EDIM + h*HD + nf*16 + l16] = f2bf(oacc[nf][r] * inv);
    }
  }
}

// ---------------- CLS grouped attention ----------------
__global__ __launch_bounds__(256) void cls_attn(
    const __hip_bfloat16* __restrict__ qkv,
    const __hip_bfloat16* __restrict__ mask,
    const int* __restrict__ top_idx,
    __hip_bfloat16* __restrict__ Sg_all,      // [96][16][KGP]
    __hip_bfloat16* __restrict__ x1buf)       // [BSZ][768]
{
  __shared__ __hip_bfloat16 lQ[16*64];
  __shared__ __hip_bfloat16 lV[256*64];       // swizzled V rows per 256-key chunk
  __shared__ float red[16][17];
  __shared__ float rmax[16];
  __shared__ float rsum[16];

  const int tid = threadIdx.x;
  const int g = blockIdx.x / NH;
  const int h = blockIdx.x % NH;
  __hip_bfloat16* Sg = Sg_all + (size_t)blockIdx.x * 16 * KGP;
  const int wave = tid >> 6, lane = tid & 63;
  const int l16 = lane & 15, kq = lane >> 4, o4 = (lane >> 4) * 4;

  if (tid < 128) {
    int qi = tid >> 3, c8 = tid & 7;
    int ib = g*NF + qi;
    int top = top_idx[ib];
    f32x4 v = *(const f32x4*)(qkv + ((size_t)ib*TGT + top)*QKV_N + h*HD + c8*8);
    *(f32x4*)(lQ + qi*64 + c8*8) = v;
  }
  __syncthreads();

  s16x8 q8[2];
  #pragma unroll
  for (int kk = 0; kk < 2; ++kk)
    q8[kk] = *(const s16x8*)(lQ + l16*64 + kk*32 + kq*8);

  // S1 = q1 Kg^T * scale + mask_g
  for (int nf = wave; nf < 208; nf += 4) {
    const int key = nf*16 + l16;
    if (nf < 197) {
      f32x4 a = {0.f,0.f,0.f,0.f};
      const size_t krow = (size_t)g*KG + key;
      #pragma unroll
      for (int kk = 0; kk < 2; ++kk) {
        s16x8 k8 = *(const s16x8*)(qkv + krow*QKV_N + EDIM + h*HD + kk*32 + kq*8);
        a = __builtin_amdgcn_mfma_f32_16x16x32_bf16(q8[kk], k8, a, 0, 0, 0);
      }
      const int f = key / 197;
      const int t = key - f*197;
      const float mval = bf2f(mask[((size_t)(g*NF + f)*TGT + (TGT-1))*TGT + t]);
      #pragma unroll
      for (int r = 0; r < 4; ++r)
        Sg[(o4 + r)*KGP + key] = f2bf(a[r]*0.125f + mval);
    } else {
      #pragma unroll
      for (int r = 0; r < 4; ++r)
        Sg[(o4 + r)*KGP + key] = f2bf(0.f);   // pad: P stays 0
    }
  }
  __syncthreads();

  // ---- softmax over 3152 cols; 16 threads/row, vectorized 8-wide ----
  {
    const int q = tid >> 4, c = tid & 15;
    float mx = -1e30f;
    for (int gch = c; gch < 394; gch += 16) {
      s16x8 sv = *(const s16x8*)(Sg + q*KGP + gch*8);
      #pragma unroll
      for (int j = 0; j < 8; ++j) mx = fmaxf(mx, b2f((unsigned short)sv[j]));
    }
    red[q][c] = mx;
    __syncthreads();
    if (tid < 16) {
      float m = red[tid][0];
      for (int j = 1; j < 16; ++j) m = fmaxf(m, red[tid][j]);
      rmax[tid] = m;
    }
    __syncthreads();
    const float rowmax = rmax[q];
    float sum = 0.f;
    for (int gch = c; gch < 394; gch += 16) {
      s16x8 sv = *(const s16x8*)(Sg + q*KGP + gch*8);
      s16x8 ov;
      #pragma unroll
      for (int jp = 0; jp < 4; ++jp) {
        float e0 = __expf(b2f((unsigned short)sv[2*jp])   - rowmax);
        float e1 = __expf(b2f((unsigned short)sv[2*jp+1]) - rowmax);
        sum += e0 + e1;
        unsigned int pr = packbf(e0, e1);
        ov[2*jp]   = (short)(pr & 0xffff);
        ov[2*jp+1] = (short)(pr >> 16);
      }
      *(s16x8*)(Sg + q*KGP + gch*8) = ov;
    }
    red[q][c] = sum;
    __syncthreads();
    if (tid < 16) {
      float s = 0.f;
      for (int j = 0; j < 16; ++j) s += red[tid][j];
      rsum[tid] = s;
    }
  }

  // ---- PV over 256-key chunks: swizzled V rows + direct-reg B-frags ----
  f32x4 oa = {0.f,0.f,0.f,0.f};
  const f32x4 z = {0.f,0.f,0.f,0.f};
  for (int ck = 0; ck < KGP; ck += 256) {
    __syncthreads();
    for (int idx = tid; idx < 256*8; idx += 256) {
      int t2 = idx >> 3, c8 = idx & 7;
      int key = ck + t2;
      f32x4 v = z;
      if (key < KG) v = *(const f32x4*)(qkv + ((size_t)g*KG + key)*QKV_N + 2*EDIM + h*HD + c8*8);
      *(f32x4*)(lV + swz(t2, c8*8)) = v;
    }
    __syncthreads();
    #pragma unroll
    for (int ks = 0; ks < 8; ++ks) {
      s16x8 pa = *(const s16x8*)(Sg + l16*KGP + ck + ks*32 + kq*8);
      s16x8 vf;
      #pragma unroll
      for (int j = 0; j < 8; ++j) {
        const int t2 = ks*32 + kq*8 + j;
        vf[j] = *(const short*)(lV + swz(t2, wave*16 + l16));
      }
      oa = __builtin_amdgcn_mfma_f32_16x16x32_bf16(pa, vf, oa, 0, 0, 0);
    }
  }
  #pragma unroll
  for (int r = 0; r < 4; ++r) {
    int q = o4 + r;
    int ib = g*NF + q;
    x1buf[(size_t)ib*EDIM + h*HD + wave*16 + l16] = f2bf(oa[r] / rsum[q]);
  }
}

// ---------------- LoRA head + CLS row update ----------------
__global__ __launch_bounds__(256) void final_update(
    void* __restrict__ out,
    const __hip_bfloat16* __restrict__ x1p,
    const __hip_bfloat16* __restrict__ dw, const __hip_bfloat16* __restrict__ db,
    const __hip_bfloat16* __restrict__ uw, const __hip_bfloat16* __restrict__ ub,
    const int* __restrict__ top_idx, const int* __restrict__ flag)
{
  __shared__ float x0[EDIM];
  __shared__ float hmid[64];
  const int i = blockIdx.x;
  const int tid = threadIdx.x;
  const int top = top_idx[i];
  const int isbf = *flag;
  const size_t rowoff = ((size_t)i*TGT + top)*EDIM;
  for (int e = tid; e < EDIM; e += 256)
    x0[e] = isbf ? bf2f(((const __hip_bfloat16*)out)[rowoff + e])
                 : ((const float*)out)[rowoff + e];
  __syncthreads();
  if (tid < 64) {
    float a = bf2f(db[tid]);
    for (int e = 0; e < EDIM; ++e) a += x0[e] * bf2f(dw[tid*EDIM + e]);
    hmid[tid] = a / (1.f + __expf(-1.702f * a));
  }
  __syncthreads();
  for (int e = tid; e < EDIM; e += 256) {
    float a = bf2f(ub[e]) + bf2f(x1p[(size_t)i*EDIM + e]);
    #pragma unroll
    for (int r = 0; r < 64; ++r) a += hmid[r] * bf2f(uw[e*64 + r]);
    if (isbf) ((__hip_bfloat16*)out)[rowoff + e] = f2bf(a);
    else ((float*)out)[rowoff + e] = a;
  }
}

extern "C" void kernel_launch(void* const* d_in, const int* in_sizes, int n_in,
                              void* d_out, int out_size, void* d_ws, size_t ws_size,
                              hipStream_t stream) {
  (void)in_sizes; (void)n_in; (void)out_size; (void)ws_size;
  const int* top_idx = (const int*)d_in[13];

  char* ws = (char*)d_ws;
  size_t off = 0;
  auto alloc = [&](size_t bytes) { char* p = ws + off; off += (bytes + 15) & ~(size_t)15; return p; };

  int* flag = (int*)alloc(16);
  __hip_bfloat16* x_c    = (__hip_bfloat16*)alloc((size_t)19365888*2);
  __hip_bfloat16* mask_c = (__hip_bfloat16*)alloc((size_t)4967552*2);
  __hip_bfloat16* wIn_c  = (__hip_bfloat16*)alloc((size_t)1769472*2);
  __hip_bfloat16* bIn_c  = (__hip_bfloat16*)alloc((size_t)2304*2);
  __hip_bfloat16* wOut_c = (__hip_bfloat16*)alloc((size_t)589824*2);
  __hip_bfloat16* bOut_c = (__hip_bfloat16*)alloc((size_t)768*2);
  __hip_bfloat16* la_c   = (__hip_bfloat16*)alloc((size_t)49152*2);
  __hip_bfloat16* lb_c   = (__hip_bfloat16*)alloc((size_t)147456*2);
  __hip_bfloat16* dw_c   = (__hip_bfloat16*)alloc((size_t)49152*2);
  __hip_bfloat16* db_c   = (__hip_bfloat16*)alloc((size_t)64*2);
  __hip_bfloat16* uw_c   = (__hip_bfloat16*)alloc((size_t)49152*2);
  __hip_bfloat16* ub_c   = (__hip_bfloat16*)alloc((size_t)768*2);
  __hip_bfloat16* Wc     = (__hip_bfloat16*)alloc((size_t)QKV_N*EDIM*2);
  __hip_bfloat16* qkv    = (__hip_bfloat16*)alloc((size_t)M_TOT*QKV_N*2);
  __hip_bfloat16* xop    = (__hip_bfloat16*)alloc((size_t)M_TOT*EDIM*2);
  __hip_bfloat16* x1b    = (__hip_bfloat16*)alloc((size_t)BSZ*EDIM*2);
  __hip_bfloat16* x1p    = (__hip_bfloat16*)alloc((size_t)BSZ*EDIM*2);
  __hip_bfloat16* Sg     = (__hip_bfloat16*)alloc((size_t)96*16*KGP*2);

  detect_dtype<<<1, 64, 0, stream>>>((const unsigned short*)d_in[0], flag);

  auto CV = [&](int idx, __hip_bfloat16* dst, int n) {
    int n8 = n / 8;
    int grid = (n8 + 255) / 256; if (grid > 2048) grid = 2048; if (grid < 1) grid = 1;
    convert_bf16<<<grid, 256, 0, stream>>>(d_in[idx], dst, n8, flag);
  };
  CV(0,  x_c,    19365888);
  CV(1,  mask_c, 4967552);
  CV(2,  wIn_c,  1769472);
  CV(3,  bIn_c,  2304);
  CV(4,  wOut_c, 589824);
  CV(5,  bOut_c, 768);
  CV(6,  la_c,   49152);
  CV(7,  lb_c,   147456);
  CV(8,  dw_c,   49152);
  CV(9,  db_c,   64);
  CV(10, uw_c,   49152);
  CV(11, ub_c,   768);

  build_wc<<<2304, 256, 0, stream>>>(wIn_c, la_c, lb_c, Wc);
  gemm_bt_bias<<<dim3(197, 18), 256, 0, stream>>>(x_c, Wc, bIn_c, qkv, M_TOT, QKV_N, EDIM, flag, 0);
  attn_fused<<<dim3(6144), 256, 0, stream>>>(qkv, mask_c, xop);
  gemm_bt_bias<<<dim3(197, 6), 256, 0, stream>>>(xop, wOut_c, bOut_c, d_out, M_TOT, EDIM, EDIM, flag, 1);
  cls_attn<<<dim3(96), 256, 0, stream>>>(qkv, mask_c, top_idx, Sg, x1b);
  gemm_bt_bias<<<dim3(1, 6), 256, 0, stream>>>(x1b, wOut_c, bOut_c, x1p, BSZ, EDIM, EDIM, flag, 0);
  final_update<<<128, 256, 0, stream>>>(d_out, x1p, dw_c, db_c, uw_c, ub_c, top_idx, flag);
}

// Round 5
// 684.682 us; speedup vs baseline: 1.7019x; 1.0654x over previous
//
#include <hip/hip_runtime.h>
#include <hip/hip_bf16.h>

typedef __attribute__((ext_vector_type(4))) float f32x4;
typedef __attribute__((ext_vector_type(8))) short s16x8;

#define BSZ 128
#define TGT 197
#define EDIM 768
#define NH 12
#define HD 64
#define NF 16
#define M_TOT (BSZ*TGT)      // 25216
#define QKV_N (3*EDIM)       // 2304
#define KG (NF*TGT)          // 3152
#define KGP 3328             // KG padded to multiple of 256

__device__ __forceinline__ float b2f(unsigned short u) {
  return __uint_as_float(((unsigned int)u) << 16);
}
__device__ __forceinline__ float bf2f(__hip_bfloat16 b) { return __bfloat162float(b); }
__device__ __forceinline__ __hip_bfloat16 f2bf(float f) { return __float2bfloat16(f); }
__device__ __forceinline__ unsigned int packbf(float a, float b) {
  __hip_bfloat16 x = __float2bfloat16(a), y = __float2bfloat16(b);
  return (unsigned int)*(unsigned short*)&x | ((unsigned int)*(unsigned short*)&y << 16);
}
// swizzled short-index into a [T][64] bf16 LDS tile (attn kernels)
__device__ __forceinline__ int swz(int t, int c) {
  return t*64 + (c ^ ((((t & 7) ^ ((t >> 3) & 3))) << 3));
}

__device__ __forceinline__ void gload_lds16(const void* gsrc, void* ldst) {
  __builtin_amdgcn_global_load_lds(
      (const __attribute__((address_space(1))) unsigned int*)gsrc,
      (__attribute__((address_space(3))) unsigned int*)ldst, 16, 0, 0);
}

// ---------------- dtype detection: 1 = bf16 storage, 0 = f32 storage ----------------
__global__ void detect_dtype(const unsigned short* __restrict__ xraw, int* __restrict__ flag) {
  if (threadIdx.x == 0 && blockIdx.x == 0) {
    float mx = 0.f;
    for (int j = 0; j < 1024; ++j) {
      float v = fabsf(b2f(xraw[j]));
      if (v < 1e30f) mx = fmaxf(mx, v);
      else mx = 1e30f;
    }
    *flag = (mx < 100.0f) ? 1 : 0;
  }
}

// ---------------- canonicalize float tensor to bf16 (skippable when already bf16) ----
__global__ __launch_bounds__(256) void convert_bf16(
    const void* __restrict__ src, __hip_bfloat16* __restrict__ dst,
    int n8, const int* __restrict__ flag, int skip_if_bf)
{
  const int isbf = *flag;
  if (skip_if_bf && isbf) return;   // downstream selects the raw pointer
  int i = blockIdx.x * 256 + threadIdx.x;
  const int stride = gridDim.x * 256;
  if (isbf) {
    const s16x8* s = (const s16x8*)src;
    s16x8* d = (s16x8*)dst;
    for (; i < n8; i += stride) d[i] = s[i];
  } else {
    const f32x4* s = (const f32x4*)src;
    s16x8* d = (s16x8*)dst;
    for (; i < n8; i += stride) {
      f32x4 a = s[i*2], b = s[i*2+1];
      s16x8 o;
      #pragma unroll
      for (int j = 0; j < 4; ++j) { __hip_bfloat16 t = f2bf(a[j]); o[j] = *(short*)&t; }
      #pragma unroll
      for (int j = 0; j < 4; ++j) { __hip_bfloat16 t = f2bf(b[j]); o[4+j] = *(short*)&t; }
      d[i] = o;
    }
  }
}

// ---------------- Wc = in_proj_weight + lora_b @ lora_a ----------------
__global__ __launch_bounds__(256) void build_wc(
    const __hip_bfloat16* __restrict__ W,
    const __hip_bfloat16* __restrict__ la,
    const __hip_bfloat16* __restrict__ lb,
    __hip_bfloat16* __restrict__ Wc)
{
  __shared__ float lbr[64];
  const int n = blockIdx.x;
  if (threadIdx.x < 64) lbr[threadIdx.x] = bf2f(lb[n*64 + threadIdx.x]);
  __syncthreads();
  for (int e = threadIdx.x; e < EDIM; e += 256) {
    float acc = bf2f(W[(size_t)n*EDIM + e]);
    for (int r = 0; r < 64; ++r) acc += lbr[r] * bf2f(la[r*EDIM + e]);
    Wc[(size_t)n*EDIM + e] = f2bf(acc);
  }
}

// ---------------- GEMM: C[M][N] = A[M][K] @ B[N][K]^T + bias ----------------
// 1D grid = (M/128)*(N/128); chunked-XCD bijective swizzle, n-fastest within stripe.
__global__ __launch_bounds__(256) void gemm_bt_bias(
    const __hip_bfloat16* __restrict__ A,
    const __hip_bfloat16* __restrict__ A_alt,
    const __hip_bfloat16* __restrict__ B,
    const __hip_bfloat16* __restrict__ bias,
    void* __restrict__ C,
    int M, int N, int K, int ntiles,
    const int* __restrict__ flag, int flag_mode)
{
  __shared__ __hip_bfloat16 lA[128*32];
  __shared__ __hip_bfloat16 lB[128*32];
  const int tid = threadIdx.x;
  const int wave = tid >> 6, lane = tid & 63;
  const int l16 = lane & 15, kq = lane >> 4;

  // bijective chunked-XCD swizzle (m204): contiguous wgid chunk per XCD
  const int nwg = gridDim.x;
  const int bid = blockIdx.x;
  const int qc = nwg >> 3, rc = nwg & 7;
  const int xcd = bid & 7;
  const int wgid = (xcd < rc ? xcd*(qc+1) : rc*(qc+1) + (xcd-rc)*qc) + (bid >> 3);
  const long brow = (long)(wgid / ntiles) * 128;
  const long bcol = (long)(wgid % ntiles) * 128;

  const int isbf = *flag;
  const __hip_bfloat16* Ause = isbf ? A_alt : A;

  const int wr = (wave >> 1) * 64;
  const int wc = (wave & 1) * 64;
  const int sr = tid >> 2;
  const int sc = (tid & 3) * 8;

  f32x4 acc[4][4];
  #pragma unroll
  for (int i = 0; i < 4; i++)
    #pragma unroll
    for (int j = 0; j < 4; j++) acc[i][j] = (f32x4){0.f,0.f,0.f,0.f};

  char* lAb = (char*)lA;
  char* lBb = (char*)lB;
  const int wbase = wave * 1024;

  for (int k0 = 0; k0 < K; k0 += 32) {
    __syncthreads();
    gload_lds16(Ause + (brow + sr)      * (long)K + k0 + sc, lAb + wbase);
    gload_lds16(Ause + (brow + sr + 64) * (long)K + k0 + sc, lAb + 4096 + wbase);
    gload_lds16(B + (bcol + sr)      * (long)K + k0 + sc, lBb + wbase);
    gload_lds16(B + (bcol + sr + 64) * (long)K + k0 + sc, lBb + 4096 + wbase);
    __syncthreads();
    s16x8 af[4], bfr[4];
    #pragma unroll
    for (int mi = 0; mi < 4; mi++)
      af[mi] = *(const s16x8*)(lAb + ((wr + mi*16 + l16)*32 + kq*8)*2);
    #pragma unroll
    for (int ni = 0; ni < 4; ni++)
      bfr[ni] = *(const s16x8*)(lBb + ((wc + ni*16 + l16)*32 + kq*8)*2);
    #pragma unroll
    for (int mi = 0; mi < 4; mi++)
      #pragma unroll
      for (int ni = 0; ni < 4; ni++)
        acc[mi][ni] = __builtin_amdgcn_mfma_f32_16x16x32_bf16(af[mi], bfr[ni], acc[mi][ni], 0, 0, 0);
  }

  const int o4 = (lane >> 4) * 4;
  __syncthreads();   // protect lA reuse by the epilogue

  const int f32o = flag_mode && (!isbf);
  if (!f32o) {
    // vectorized epilogue: per-wave 16x64 LDS bounce (XOR-swizzled), 16B stores
    __hip_bfloat16* eb = lA + wave*1024;      // 2 KB per wave
    __hip_bfloat16* Cb = (__hip_bfloat16*)C;
    const int rr = lane >> 3, cg = lane & 7;
    #pragma unroll
    for (int mi = 0; mi < 4; ++mi) {
      #pragma unroll
      for (int ni = 0; ni < 4; ++ni) {
        const long col = bcol + wc + ni*16 + l16;
        const float bv = bf2f(bias[col]);
        #pragma unroll
        for (int r = 0; r < 4; ++r) {
          const int row16 = o4 + r;
          const int sidx = row16*64 + ((((ni*2 + (l16 >> 3)) ^ (row16 & 7)) << 3) | (l16 & 7));
          eb[sidx] = f2bf(acc[mi][ni][r] + bv);
        }
      }
      asm volatile("s_waitcnt lgkmcnt(0)" ::: "memory");
      __builtin_amdgcn_sched_barrier(0);
      #pragma unroll
      for (int pass = 0; pass < 2; ++pass) {
        const int row16 = pass*8 + rr;
        const int sidx = row16*64 + ((cg ^ (row16 & 7)) << 3);
        s16x8 v = *(const s16x8*)(eb + sidx);
        *(s16x8*)(Cb + (brow + wr + mi*16 + row16) * (long)N + bcol + wc + cg*8) = v;
      }
      asm volatile("s_waitcnt lgkmcnt(0)" ::: "memory");
      __builtin_amdgcn_sched_barrier(0);
    }
  } else {
    // f32 output fallback (only used when storage is f32)
    #pragma unroll
    for (int ni = 0; ni < 4; ni++) {
      const long col = bcol + wc + ni*16 + l16;
      const float bv = bf2f(bias[col]);
      #pragma unroll
      for (int mi = 0; mi < 4; mi++) {
        #pragma unroll
        for (int r = 0; r < 4; r++) {
          const long row = brow + wr + mi*16 + o4 + r;
          ((float*)C)[row * (long)N + col] = acc[mi][ni][r] + bv;
        }
      }
    }
  }
}

// ---------------- fused attention, swapped-QK^T in-register softmax ----------------
__global__ __launch_bounds__(256) void attn_fused(
    const __hip_bfloat16* __restrict__ qkv,      // [M_TOT][2304]
    const __hip_bfloat16* __restrict__ mask,     // converted
    const __hip_bfloat16* __restrict__ mask_raw, // raw (valid iff *flag==1)
    const int* __restrict__ flag,
    __hip_bfloat16* __restrict__ xop)            // [M_TOT][768]
{
  __shared__ __hip_bfloat16 lK[224*64];
  __shared__ __hip_bfloat16 lV[224*64];

  const int tid = threadIdx.x;
  const int blk = blockIdx.x;
  const int xcd = blk & 7;
  const int slot = blk >> 3;            // 0..767
  const int ih = xcd * 192 + (slot >> 2);
  const int qt = slot & 3;
  const int h = ih % NH;
  const int i = ih / NH;
  const int q0 = qt * 64;
  const size_t rowbase = (size_t)i * TGT;
  const int wave = tid >> 6, lane = tid & 63;
  const int l16 = lane & 15, kq = lane >> 4;
  const __hip_bfloat16* msk = (*flag) ? mask_raw : mask;

  const f32x4 z = {0.f,0.f,0.f,0.f};
  for (int idx = tid; idx < 224*8; idx += 256) {
    int t = idx >> 3, c8 = idx & 7;
    f32x4 kv = z, vv = z;
    if (t < TGT) {
      kv = *(const f32x4*)(qkv + (rowbase + t)*QKV_N + EDIM   + h*HD + c8*8);
      vv = *(const f32x4*)(qkv + (rowbase + t)*QKV_N + 2*EDIM + h*HD + c8*8);
    }
    *(f32x4*)(lK + swz(t, c8*8)) = kv;
    *(f32x4*)(lV + swz(t, c8*8)) = vv;
  }

  int qr = q0 + wave*16 + l16;
  const int qrc = qr > TGT-1 ? TGT-1 : qr;
  s16x8 qf[2];
  #pragma unroll
  for (int kk = 0; kk < 2; ++kk)
    qf[kk] = *(const s16x8*)(qkv + (rowbase + qrc)*QKV_N + h*HD + kk*32 + kq*8);

  __syncthreads();

  f32x4 acc[14];
  #pragma unroll
  for (int nf = 0; nf < 14; ++nf) {
    acc[nf] = (f32x4){0.f,0.f,0.f,0.f};
    #pragma unroll
    for (int kk = 0; kk < 2; ++kk) {
      s16x8 kf = *(const s16x8*)(lK + swz(nf*16 + l16, kk*32 + kq*8));
      acc[nf] = __builtin_amdgcn_mfma_f32_16x16x32_bf16(kf, qf[kk], acc[nf], 0, 0, 0);
    }
  }

  float mx = -1e30f;
  #pragma unroll
  for (int nf = 0; nf < 14; ++nf) {
    #pragma unroll
    for (int r = 0; r < 4; ++r) {
      const int t = nf*16 + kq*4 + r;
      float s;
      if (t < TGT) s = acc[nf][r]*0.125f + bf2f(msk[(rowbase + qrc)*TGT + t]);
      else s = -1e30f;
      acc[nf][r] = s;
      mx = fmaxf(mx, s);
    }
  }
  mx = fmaxf(mx, __shfl_xor(mx, 16));
  mx = fmaxf(mx, __shfl_xor(mx, 32));

  float rs = 0.f;
  unsigned int pk[14][2];
  #pragma unroll
  for (int nf = 0; nf < 14; ++nf) {
    float p0 = __expf(acc[nf][0] - mx);
    float p1 = __expf(acc[nf][1] - mx);
    float p2 = __expf(acc[nf][2] - mx);
    float p3 = __expf(acc[nf][3] - mx);
    rs += (p0 + p1) + (p2 + p3);
    pk[nf][0] = packbf(p0, p1);
    pk[nf][1] = packbf(p2, p3);
  }
  rs += __shfl_xor(rs, 16);
  rs += __shfl_xor(rs, 32);

  f32x4 oacc[4];
  #pragma unroll
  for (int nf = 0; nf < 4; ++nf) oacc[nf] = (f32x4){0.f,0.f,0.f,0.f};

  const int slbase = l16 + ((kq & 1) << 5);
  #pragma unroll
  for (int kt = 0; kt < 7; ++kt) {
    s16x8 pa;
    #pragma unroll
    for (int jp = 0; jp < 4; ++jp) {
      const int srcLane = slbase + ((jp >> 1) << 4);
      int va = __shfl((int)pk[2*kt][jp & 1], srcLane, 64);
      int vb = __shfl((int)pk[2*kt + 1][jp & 1], srcLane, 64);
      int sel = (kq < 2) ? va : vb;
      pa[2*jp]     = (short)(sel & 0xffff);
      pa[2*jp + 1] = (short)(((unsigned int)sel) >> 16);
    }
    #pragma unroll
    for (int nf = 0; nf < 4; ++nf) {
      s16x8 vf;
      #pragma unroll
      for (int j = 0; j < 8; ++j) {
        const int t = kt*32 + kq*8 + j;
        vf[j] = *(const short*)(lV + swz(t, nf*16 + l16));
      }
      oacc[nf] = __builtin_amdgcn_mfma_f32_16x16x32_bf16(pa, vf, oacc[nf], 0, 0, 0);
    }
  }

  #pragma unroll
  for (int r = 0; r < 4; ++r) {
    const float rsrc = __shfl(rs, kq*4 + r, 64);
    const int qw = q0 + wave*16 + kq*4 + r;
    if (qw < TGT) {
      const float inv = 1.0f / rsrc;
      #pragma unroll
      for (int nf = 0; nf < 4; ++nf)
        xop[(rowbase + qw)*(size_t)EDIM + h*HD + nf*16 + l16] = f2bf(oacc[nf][r] * inv);
    }
  }
}

// ---------------- CLS grouped attention ----------------
__global__ __launch_bounds__(256) void cls_attn(
    const __hip_bfloat16* __restrict__ qkv,
    const __hip_bfloat16* __restrict__ mask,
    const __hip_bfloat16* __restrict__ mask_raw,
    const int* __restrict__ flag,
    const int* __restrict__ top_idx,
    __hip_bfloat16* __restrict__ Sg_all,      // [96][16][KGP]
    __hip_bfloat16* __restrict__ x1buf)       // [BSZ][768]
{
  __shared__ __hip_bfloat16 lQ[16*64];
  __shared__ __hip_bfloat16 lV[256*64];
  __shared__ float red[16][17];
  __shared__ float rmax[16];
  __shared__ float rsum[16];

  const int tid = threadIdx.x;
  const int g = blockIdx.x / NH;
  const int h = blockIdx.x % NH;
  __hip_bfloat16* Sg = Sg_all + (size_t)blockIdx.x * 16 * KGP;
  const int wave = tid >> 6, lane = tid & 63;
  const int l16 = lane & 15, kq = lane >> 4, o4 = (lane >> 4) * 4;
  const __hip_bfloat16* msk = (*flag) ? mask_raw : mask;

  if (tid < 128) {
    int qi = tid >> 3, c8 = tid & 7;
    int ib = g*NF + qi;
    int top = top_idx[ib];
    f32x4 v = *(const f32x4*)(qkv + ((size_t)ib*TGT + top)*QKV_N + h*HD + c8*8);
    *(f32x4*)(lQ + qi*64 + c8*8) = v;
  }
  __syncthreads();

  s16x8 q8[2];
  #pragma unroll
  for (int kk = 0; kk < 2; ++kk)
    q8[kk] = *(const s16x8*)(lQ + l16*64 + kk*32 + kq*8);

  for (int nf = wave; nf < 208; nf += 4) {
    const int key = nf*16 + l16;
    if (nf < 197) {
      f32x4 a = {0.f,0.f,0.f,0.f};
      const size_t krow = (size_t)g*KG + key;
      #pragma unroll
      for (int kk = 0; kk < 2; ++kk) {
        s16x8 k8 = *(const s16x8*)(qkv + krow*QKV_N + EDIM + h*HD + kk*32 + kq*8);
        a = __builtin_amdgcn_mfma_f32_16x16x32_bf16(q8[kk], k8, a, 0, 0, 0);
      }
      const int f = key / 197;
      const int t = key - f*197;
      const float mval = bf2f(msk[((size_t)(g*NF + f)*TGT + (TGT-1))*TGT + t]);
      #pragma unroll
      for (int r = 0; r < 4; ++r)
        Sg[(o4 + r)*KGP + key] = f2bf(a[r]*0.125f + mval);
    } else {
      #pragma unroll
      for (int r = 0; r < 4; ++r)
        Sg[(o4 + r)*KGP + key] = f2bf(0.f);
    }
  }
  __syncthreads();

  {
    const int q = tid >> 4, c = tid & 15;
    float mx = -1e30f;
    for (int gch = c; gch < 394; gch += 16) {
      s16x8 sv = *(const s16x8*)(Sg + q*KGP + gch*8);
      #pragma unroll
      for (int j = 0; j < 8; ++j) mx = fmaxf(mx, b2f((unsigned short)sv[j]));
    }
    red[q][c] = mx;
    __syncthreads();
    if (tid < 16) {
      float m = red[tid][0];
      for (int j = 1; j < 16; ++j) m = fmaxf(m, red[tid][j]);
      rmax[tid] = m;
    }
    __syncthreads();
    const float rowmax = rmax[q];
    float sum = 0.f;
    for (int gch = c; gch < 394; gch += 16) {
      s16x8 sv = *(const s16x8*)(Sg + q*KGP + gch*8);
      s16x8 ov;
      #pragma unroll
      for (int jp = 0; jp < 4; ++jp) {
        float e0 = __expf(b2f((unsigned short)sv[2*jp])   - rowmax);
        float e1 = __expf(b2f((unsigned short)sv[2*jp+1]) - rowmax);
        sum += e0 + e1;
        unsigned int pr = packbf(e0, e1);
        ov[2*jp]   = (short)(pr & 0xffff);
        ov[2*jp+1] = (short)(pr >> 16);
      }
      *(s16x8*)(Sg + q*KGP + gch*8) = ov;
    }
    red[q][c] = sum;
    __syncthreads();
    if (tid < 16) {
      float s = 0.f;
      for (int j = 0; j < 16; ++j) s += red[tid][j];
      rsum[tid] = s;
    }
  }

  f32x4 oa = {0.f,0.f,0.f,0.f};
  const f32x4 z = {0.f,0.f,0.f,0.f};
  for (int ck = 0; ck < KGP; ck += 256) {
    __syncthreads();
    for (int idx = tid; idx < 256*8; idx += 256) {
      int t2 = idx >> 3, c8 = idx & 7;
      int key = ck + t2;
      f32x4 v = z;
      if (key < KG) v = *(const f32x4*)(qkv + ((size_t)g*KG + key)*QKV_N + 2*EDIM + h*HD + c8*8);
      *(f32x4*)(lV + swz(t2, c8*8)) = v;
    }
    __syncthreads();
    #pragma unroll
    for (int ks = 0; ks < 8; ++ks) {
      s16x8 pa = *(const s16x8*)(Sg + l16*KGP + ck + ks*32 + kq*8);
      s16x8 vf;
      #pragma unroll
      for (int j = 0; j < 8; ++j) {
        const int t2 = ks*32 + kq*8 + j;
        vf[j] = *(const short*)(lV + swz(t2, wave*16 + l16));
      }
      oa = __builtin_amdgcn_mfma_f32_16x16x32_bf16(pa, vf, oa, 0, 0, 0);
    }
  }
  #pragma unroll
  for (int r = 0; r < 4; ++r) {
    int q = o4 + r;
    int ib = g*NF + q;
    x1buf[(size_t)ib*EDIM + h*HD + wave*16 + l16] = f2bf(oa[r] / rsum[q]);
  }
}

// ---------------- LoRA head + CLS row update ----------------
__global__ __launch_bounds__(256) void final_update(
    void* __restrict__ out,
    const __hip_bfloat16* __restrict__ x1p,
    const __hip_bfloat16* __restrict__ dw, const __hip_bfloat16* __restrict__ db,
    const __hip_bfloat16* __restrict__ uw, const __hip_bfloat16* __restrict__ ub,
    const int* __restrict__ top_idx, const int* __restrict__ flag)
{
  __shared__ float x0[EDIM];
  __shared__ float hmid[64];
  const int i = blockIdx.x;
  const int tid = threadIdx.x;
  const int top = top_idx[i];
  const int isbf = *flag;
  const size_t rowoff = ((size_t)i*TGT + top)*EDIM;
  for (int e = tid; e < EDIM; e += 256)
    x0[e] = isbf ? bf2f(((const __hip_bfloat16*)out)[rowoff + e])
                 : ((const float*)out)[rowoff + e];
  __syncthreads();
  if (tid < 64) {
    float a = bf2f(db[tid]);
    for (int e = 0; e < EDIM; ++e) a += x0[e] * bf2f(dw[tid*EDIM + e]);
    hmid[tid] = a / (1.f + __expf(-1.702f * a));
  }
  __syncthreads();
  for (int e = tid; e < EDIM; e += 256) {
    float a = bf2f(ub[e]) + bf2f(x1p[(size_t)i*EDIM + e]);
    #pragma unroll
    for (int r = 0; r < 64; ++r) a += hmid[r] * bf2f(uw[e*64 + r]);
    if (isbf) ((__hip_bfloat16*)out)[rowoff + e] = f2bf(a);
    else ((float*)out)[rowoff + e] = a;
  }
}

extern "C" void kernel_launch(void* const* d_in, const int* in_sizes, int n_in,
                              void* d_out, int out_size, void* d_ws, size_t ws_size,
                              hipStream_t stream) {
  (void)in_sizes; (void)n_in; (void)out_size; (void)ws_size;
  const int* top_idx = (const int*)d_in[13];
  const __hip_bfloat16* x_raw    = (const __hip_bfloat16*)d_in[0];
  const __hip_bfloat16* mask_raw = (const __hip_bfloat16*)d_in[1];

  char* ws = (char*)d_ws;
  size_t off = 0;
  auto alloc = [&](size_t bytes) { char* p = ws + off; off += (bytes + 15) & ~(size_t)15; return p; };

  int* flag = (int*)alloc(16);
  __hip_bfloat16* x_c    = (__hip_bfloat16*)alloc((size_t)19365888*2);
  __hip_bfloat16* mask_c = (__hip_bfloat16*)alloc((size_t)4967552*2);
  __hip_bfloat16* wIn_c  = (__hip_bfloat16*)alloc((size_t)1769472*2);
  __hip_bfloat16* bIn_c  = (__hip_bfloat16*)alloc((size_t)2304*2);
  __hip_bfloat16* wOut_c = (__hip_bfloat16*)alloc((size_t)589824*2);
  __hip_bfloat16* bOut_c = (__hip_bfloat16*)alloc((size_t)768*2);
  __hip_bfloat16* la_c   = (__hip_bfloat16*)alloc((size_t)49152*2);
  __hip_bfloat16* lb_c   = (__hip_bfloat16*)alloc((size_t)147456*2);
  __hip_bfloat16* dw_c   = (__hip_bfloat16*)alloc((size_t)49152*2);
  __hip_bfloat16* db_c   = (__hip_bfloat16*)alloc((size_t)64*2);
  __hip_bfloat16* uw_c   = (__hip_bfloat16*)alloc((size_t)49152*2);
  __hip_bfloat16* ub_c   = (__hip_bfloat16*)alloc((size_t)768*2);
  __hip_bfloat16* Wc     = (__hip_bfloat16*)alloc((size_t)QKV_N*EDIM*2);
  __hip_bfloat16* qkv    = (__hip_bfloat16*)alloc((size_t)M_TOT*QKV_N*2);
  __hip_bfloat16* xop    = (__hip_bfloat16*)alloc((size_t)M_TOT*EDIM*2);
  __hip_bfloat16* x1b    = (__hip_bfloat16*)alloc((size_t)BSZ*EDIM*2);
  __hip_bfloat16* x1p    = (__hip_bfloat16*)alloc((size_t)BSZ*EDIM*2);
  __hip_bfloat16* Sg     = (__hip_bfloat16*)alloc((size_t)96*16*KGP*2);

  detect_dtype<<<1, 64, 0, stream>>>((const unsigned short*)d_in[0], flag);

  auto CV = [&](int idx, __hip_bfloat16* dst, int n, int skip) {
    int n8 = n / 8;
    int grid = (n8 + 255) / 256; if (grid > 2048) grid = 2048; if (grid < 1) grid = 1;
    convert_bf16<<<grid, 256, 0, stream>>>(d_in[idx], dst, n8, flag, skip);
  };
  CV(0,  x_c,    19365888, 1);   // skipped when already bf16 (gemm selects raw)
  CV(1,  mask_c, 4967552, 1);    // skipped when already bf16 (attn/cls select raw)
  CV(2,  wIn_c,  1769472, 0);
  CV(3,  bIn_c,  2304, 0);
  CV(4,  wOut_c, 589824, 0);
  CV(5,  bOut_c, 768, 0);
  CV(6,  la_c,   49152, 0);
  CV(7,  lb_c,   147456, 0);
  CV(8,  dw_c,   49152, 0);
  CV(9,  db_c,   64, 0);
  CV(10, uw_c,   49152, 0);
  CV(11, ub_c,   768, 0);

  build_wc<<<2304, 256, 0, stream>>>(wIn_c, la_c, lb_c, Wc);
  gemm_bt_bias<<<197*18, 256, 0, stream>>>(x_c, x_raw, Wc, bIn_c, qkv,
                                           M_TOT, QKV_N, EDIM, 18, flag, 0);
  attn_fused<<<dim3(6144), 256, 0, stream>>>(qkv, mask_c, mask_raw, flag, xop);
  gemm_bt_bias<<<197*6, 256, 0, stream>>>(xop, xop, wOut_c, bOut_c, d_out,
                                          M_TOT, EDIM, EDIM, 6, flag, 1);
  cls_attn<<<dim3(96), 256, 0, stream>>>(qkv, mask_c, mask_raw, flag, top_idx, Sg, x1b);
  gemm_bt_bias<<<6, 256, 0, stream>>>(x1b, x1b, wOut_c, bOut_c, x1p,
                                      BSZ, EDIM, EDIM, 6, flag, 0);
  final_update<<<128, 256, 0, stream>>>(d_out, x1p, dw_c, db_c, uw_c, ub_c, top_idx, flag);
}

// Round 6
// 603.792 us; speedup vs baseline: 1.9299x; 1.1340x over previous
//
#include <hip/hip_runtime.h>
#include <hip/hip_bf16.h>

typedef __attribute__((ext_vector_type(4))) float f32x4;
typedef __attribute__((ext_vector_type(8))) short s16x8;

#define BSZ 128
#define TGT 197
#define EDIM 768
#define NH 12
#define HD 64
#define NF 16
#define M_TOT (BSZ*TGT)      // 25216
#define QKV_N (3*EDIM)       // 2304
#define KG (NF*TGT)          // 3152
#define KGP 3328

__device__ __forceinline__ float b2f(unsigned short u) {
  return __uint_as_float(((unsigned int)u) << 16);
}
__device__ __forceinline__ float bf2f(__hip_bfloat16 b) { return __bfloat162float(b); }
__device__ __forceinline__ __hip_bfloat16 f2bf(float f) { return __float2bfloat16(f); }
__device__ __forceinline__ unsigned int packbf(float a, float b) {
  __hip_bfloat16 x = __float2bfloat16(a), y = __float2bfloat16(b);
  return (unsigned int)*(unsigned short*)&x | ((unsigned int)*(unsigned short*)&y << 16);
}
// swizzled short-index into a [T][64] bf16 LDS tile (attn kernels)
__device__ __forceinline__ int swz(int t, int c) {
  return t*64 + (c ^ ((((t & 7) ^ ((t >> 3) & 3))) << 3));
}

__device__ __forceinline__ void gload_lds16(const void* gsrc, void* ldst) {
  __builtin_amdgcn_global_load_lds(
      (const __attribute__((address_space(1))) unsigned int*)gsrc,
      (__attribute__((address_space(3))) unsigned int*)ldst, 16, 0, 0);
}

// ---------------- dtype detection ----------------
__global__ void detect_dtype(const unsigned short* __restrict__ xraw, int* __restrict__ flag) {
  if (threadIdx.x == 0 && blockIdx.x == 0) {
    float mx = 0.f;
    for (int j = 0; j < 1024; ++j) {
      float v = fabsf(b2f(xraw[j]));
      if (v < 1e30f) mx = fmaxf(mx, v);
      else mx = 1e30f;
    }
    *flag = (mx < 100.0f) ? 1 : 0;
  }
}

// ---------------- canonicalize float tensor to bf16 ----------------
__global__ __launch_bounds__(256) void convert_bf16(
    const void* __restrict__ src, __hip_bfloat16* __restrict__ dst,
    int n8, const int* __restrict__ flag, int skip_if_bf)
{
  const int isbf = *flag;
  if (skip_if_bf && isbf) return;
  int i = blockIdx.x * 256 + threadIdx.x;
  const int stride = gridDim.x * 256;
  if (isbf) {
    const s16x8* s = (const s16x8*)src;
    s16x8* d = (s16x8*)dst;
    for (; i < n8; i += stride) d[i] = s[i];
  } else {
    const f32x4* s = (const f32x4*)src;
    s16x8* d = (s16x8*)dst;
    for (; i < n8; i += stride) {
      f32x4 a = s[i*2], b = s[i*2+1];
      s16x8 o;
      #pragma unroll
      for (int j = 0; j < 4; ++j) { __hip_bfloat16 t = f2bf(a[j]); o[j] = *(short*)&t; }
      #pragma unroll
      for (int j = 0; j < 4; ++j) { __hip_bfloat16 t = f2bf(b[j]); o[4+j] = *(short*)&t; }
      d[i] = o;
    }
  }
}

// ---------------- Wc = in_proj_weight + lora_b @ lora_a ----------------
__global__ __launch_bounds__(256) void build_wc(
    const __hip_bfloat16* __restrict__ W,
    const __hip_bfloat16* __restrict__ la,
    const __hip_bfloat16* __restrict__ lb,
    __hip_bfloat16* __restrict__ Wc)
{
  __shared__ float lbr[64];
  const int n = blockIdx.x;
  if (threadIdx.x < 64) lbr[threadIdx.x] = bf2f(lb[n*64 + threadIdx.x]);
  __syncthreads();
  for (int e = threadIdx.x; e < EDIM; e += 256) {
    float acc = bf2f(W[(size_t)n*EDIM + e]);
    for (int r = 0; r < 64; ++r) acc += lbr[r] * bf2f(la[r*EDIM + e]);
    Wc[(size_t)n*EDIM + e] = f2bf(acc);
  }
}

// ---------------- 256x256 8-phase GEMM: C = A[M][K] @ B[N][K]^T + bias ----------------
// 512 thr / 8 waves (2M x 4N). BK=64, double-buffered 128 KB LDS, st-swizzled.
// Counted vmcnt pipeline; N % 256 == 0, K % 64 == 0 (and K/64 >= 2); M arbitrary.
__global__ __launch_bounds__(512) void gemm_bt_8ph(
    const __hip_bfloat16* __restrict__ A,
    const __hip_bfloat16* __restrict__ A_alt,
    const __hip_bfloat16* __restrict__ B,
    const __hip_bfloat16* __restrict__ bias,
    void* __restrict__ C,
    int M, int N, int K, int ntiles,
    const int* __restrict__ flag, int flag_mode)
{
  __shared__ char lds[131072];
  const int tid = threadIdx.x;
  const int wave = tid >> 6, lane = tid & 63;
  const int l16 = lane & 15, kq = lane >> 4;
  const int wr = wave >> 2, wc2 = wave & 3;

  // bijective chunked-XCD swizzle; n-fastest within stripe
  const int nwg = gridDim.x;
  const int bid = blockIdx.x;
  const int qc = nwg >> 3, rc = nwg & 7;
  const int xcd = bid & 7;
  const int wgid = (xcd < rc ? xcd*(qc+1) : rc*(qc+1) + (xcd-rc)*qc) + (bid >> 3);
  const long brow = (long)(wgid / ntiles) * 256;
  const long bcol = (long)(wgid % ntiles) * 256;

  const int isbf = *flag;
  const __hip_bfloat16* Ause = isbf ? A_alt : A;
  const int nkt = K >> 6;

  const int srow = tid >> 3;      // 0..63 within a staging issue
  const int schunk = tid & 7;     // 16B chunk within row
  const int wuni = wave << 10;    // wave-uniform LDS dest offset

  // stage: linear LDS dest + inverse-swizzled global source (rule 21)
  auto stA = [&](int t, int buf, int issue) {
    int ar = issue*64 + srow;
    int cs = schunk ^ (ar & 7);
    long gr = brow + ar; if (gr > (long)M - 1) gr = M - 1;
    gload_lds16(Ause + gr*(long)K + t*64 + cs*8,
                lds + buf*65536 + issue*8192 + wuni);
  };
  auto stB = [&](int t, int buf, int issue) {
    int br = issue*64 + srow;
    int cs = schunk ^ (br & 7);
    gload_lds16(B + (bcol + br)*(long)K + t*64 + cs*8,
                lds + buf*65536 + 32768 + issue*8192 + wuni);
  };
  // swizzled fragment reads
  auto rdA = [&](int buf, int q, int a, int ks) -> s16x8 {
    int ar = wr*128 + q*32 + a*16 + l16;
    int ch = ks*4 + kq;
    return *(const s16x8*)(lds + buf*65536 + ar*128 + ((ch ^ (ar & 7)) << 4));
  };
  auto rdB = [&](int buf, int ni, int ks) -> s16x8 {
    int br = wc2*64 + ni*16 + l16;
    int ch = ks*4 + kq;
    return *(const s16x8*)(lds + buf*65536 + 32768 + br*128 + ((ch ^ (br & 7)) << 4));
  };

  f32x4 acc[8][4];
  #pragma unroll
  for (int i = 0; i < 8; ++i)
    #pragma unroll
    for (int j = 0; j < 4; ++j) acc[i][j] = (f32x4){0.f,0.f,0.f,0.f};

  // prologue: stage tile 0 (order B0-3, A0, A2, A1, A3)
  stB(0,0,0); stB(0,0,1); stB(0,0,2); stB(0,0,3);
  stA(0,0,0); stA(0,0,2); stA(0,0,1); stA(0,0,3);
  asm volatile("s_waitcnt vmcnt(2)" ::: "memory");
  __builtin_amdgcn_s_barrier();

  for (int t = 0; t < nkt; ++t) {
    const int cur = t & 1, nxt = cur ^ 1;
    const bool pf = (t + 1 < nkt);
    s16x8 bfr[4][2], af[2][2];

    // ---- phase 0: B frags + A q0; prefetch B0,B1(t+1) ----
    #pragma unroll
    for (int ni = 0; ni < 4; ++ni) { bfr[ni][0] = rdB(cur,ni,0); bfr[ni][1] = rdB(cur,ni,1); }
    af[0][0]=rdA(cur,0,0,0); af[0][1]=rdA(cur,0,0,1);
    af[1][0]=rdA(cur,0,1,0); af[1][1]=rdA(cur,0,1,1);
    if (pf) { stB(t+1,nxt,0); stB(t+1,nxt,1); }
    __builtin_amdgcn_s_barrier();
    asm volatile("s_waitcnt lgkmcnt(0)" ::: "memory");
    __builtin_amdgcn_sched_barrier(0);
    __builtin_amdgcn_s_setprio(1);
    #pragma unroll
    for (int ks = 0; ks < 2; ++ks)
      #pragma unroll
      for (int ni = 0; ni < 4; ++ni) {
        acc[0][ni] = __builtin_amdgcn_mfma_f32_16x16x32_bf16(af[0][ks], bfr[ni][ks], acc[0][ni], 0,0,0);
        acc[1][ni] = __builtin_amdgcn_mfma_f32_16x16x32_bf16(af[1][ks], bfr[ni][ks], acc[1][ni], 0,0,0);
      }
    __builtin_amdgcn_s_setprio(0);

    // ---- phase 1: A q1; prefetch B2,B3(t+1); vmcnt guards A1,A3(cur) for phase 2 ----
    af[0][0]=rdA(cur,1,0,0); af[0][1]=rdA(cur,1,0,1);
    af[1][0]=rdA(cur,1,1,0); af[1][1]=rdA(cur,1,1,1);
    if (pf) {
      stB(t+1,nxt,2); stB(t+1,nxt,3);
      asm volatile("s_waitcnt vmcnt(4)" ::: "memory");
    } else {
      asm volatile("s_waitcnt vmcnt(0)" ::: "memory");
    }
    __builtin_amdgcn_s_barrier();
    asm volatile("s_waitcnt lgkmcnt(0)" ::: "memory");
    __builtin_amdgcn_sched_barrier(0);
    __builtin_amdgcn_s_setprio(1);
    #pragma unroll
    for (int ks = 0; ks < 2; ++ks)
      #pragma unroll
      for (int ni = 0; ni < 4; ++ni) {
        acc[2][ni] = __builtin_amdgcn_mfma_f32_16x16x32_bf16(af[0][ks], bfr[ni][ks], acc[2][ni], 0,0,0);
        acc[3][ni] = __builtin_amdgcn_mfma_f32_16x16x32_bf16(af[1][ks], bfr[ni][ks], acc[3][ni], 0,0,0);
      }
    __builtin_amdgcn_s_setprio(0);

    // ---- phase 2: A q2; prefetch A0,A2(t+1) ----
    af[0][0]=rdA(cur,2,0,0); af[0][1]=rdA(cur,2,0,1);
    af[1][0]=rdA(cur,2,1,0); af[1][1]=rdA(cur,2,1,1);
    if (pf) { stA(t+1,nxt,0); stA(t+1,nxt,2); }
    __builtin_amdgcn_s_barrier();
    asm volatile("s_waitcnt lgkmcnt(0)" ::: "memory");
    __builtin_amdgcn_sched_barrier(0);
    __builtin_amdgcn_s_setprio(1);
    #pragma unroll
    for (int ks = 0; ks < 2; ++ks)
      #pragma unroll
      for (int ni = 0; ni < 4; ++ni) {
        acc[4][ni] = __builtin_amdgcn_mfma_f32_16x16x32_bf16(af[0][ks], bfr[ni][ks], acc[4][ni], 0,0,0);
        acc[5][ni] = __builtin_amdgcn_mfma_f32_16x16x32_bf16(af[1][ks], bfr[ni][ks], acc[5][ni], 0,0,0);
      }
    __builtin_amdgcn_s_setprio(0);

    // ---- phase 3: A q3; prefetch A1,A3(t+1); vmcnt(2) guards t+1 phase 0 ----
    af[0][0]=rdA(cur,3,0,0); af[0][1]=rdA(cur,3,0,1);
    af[1][0]=rdA(cur,3,1,0); af[1][1]=rdA(cur,3,1,1);
    if (pf) { stA(t+1,nxt,1); stA(t+1,nxt,3); }
    asm volatile("s_waitcnt vmcnt(2)" ::: "memory");
    __builtin_amdgcn_s_barrier();
    asm volatile("s_waitcnt lgkmcnt(0)" ::: "memory");
    __builtin_amdgcn_sched_barrier(0);
    __builtin_amdgcn_s_setprio(1);
    #pragma unroll
    for (int ks = 0; ks < 2; ++ks)
      #pragma unroll
      for (int ni = 0; ni < 4; ++ni) {
        acc[6][ni] = __builtin_amdgcn_mfma_f32_16x16x32_bf16(af[0][ks], bfr[ni][ks], acc[6][ni], 0,0,0);
        acc[7][ni] = __builtin_amdgcn_mfma_f32_16x16x32_bf16(af[1][ks], bfr[ni][ks], acc[7][ni], 0,0,0);
      }
    __builtin_amdgcn_s_setprio(0);
  }

  __builtin_amdgcn_s_barrier();   // all compute done; LDS reusable for epilogue

  const int f32o = flag_mode && (!isbf);
  float bv[4];
  #pragma unroll
  for (int ni = 0; ni < 4; ++ni) bv[ni] = bf2f(bias[bcol + wc2*64 + ni*16 + l16]);
  const int o4 = kq*4;

  if (!f32o) {
    __hip_bfloat16* eb = (__hip_bfloat16*)(lds + wave*2048);  // 16x64 per-wave bounce
    __hip_bfloat16* Cb = (__hip_bfloat16*)C;
    const int rr = lane >> 3, cg = lane & 7;
    #pragma unroll
    for (int mi = 0; mi < 8; ++mi) {
      #pragma unroll
      for (int ni = 0; ni < 4; ++ni)
        #pragma unroll
        for (int r = 0; r < 4; ++r) {
          const int row16 = o4 + r;
          const int sidx = row16*64 + ((((ni*2 + (l16 >> 3)) ^ (row16 & 7)) << 3) | (l16 & 7));
          eb[sidx] = f2bf(acc[mi][ni][r] + bv[ni]);
        }
      asm volatile("s_waitcnt lgkmcnt(0)" ::: "memory");
      __builtin_amdgcn_sched_barrier(0);
      #pragma unroll
      for (int pass = 0; pass < 2; ++pass) {
        const int row16 = pass*8 + rr;
        const long grow = brow + wr*128 + mi*16 + row16;
        if (grow < M) {
          s16x8 v = *(const s16x8*)(eb + row16*64 + ((cg ^ (row16 & 7)) << 3));
          *(s16x8*)(Cb + grow*(long)N + bcol + wc2*64 + cg*8) = v;
        }
      }
      asm volatile("s_waitcnt lgkmcnt(0)" ::: "memory");
      __builtin_amdgcn_sched_barrier(0);
    }
  } else {
    #pragma unroll
    for (int mi = 0; mi < 8; ++mi)
      #pragma unroll
      for (int ni = 0; ni < 4; ++ni)
        #pragma unroll
        for (int r = 0; r < 4; ++r) {
          const long grow = brow + wr*128 + mi*16 + o4 + r;
          if (grow < M)
            ((float*)C)[grow*(long)N + bcol + wc2*64 + ni*16 + l16] = acc[mi][ni][r] + bv[ni];
        }
  }
}

// ---------------- fused attention, swapped-QK^T in-register softmax ----------------
__global__ __launch_bounds__(256) void attn_fused(
    const __hip_bfloat16* __restrict__ qkv,
    const __hip_bfloat16* __restrict__ mask,
    const __hip_bfloat16* __restrict__ mask_raw,
    const int* __restrict__ flag,
    __hip_bfloat16* __restrict__ xop)
{
  __shared__ __hip_bfloat16 lK[224*64];
  __shared__ __hip_bfloat16 lV[224*64];

  const int tid = threadIdx.x;
  const int blk = blockIdx.x;
  const int xcd = blk & 7;
  const int slot = blk >> 3;
  const int ih = xcd * 192 + (slot >> 2);
  const int qt = slot & 3;
  const int h = ih % NH;
  const int i = ih / NH;
  const int q0 = qt * 64;
  const size_t rowbase = (size_t)i * TGT;
  const int wave = tid >> 6, lane = tid & 63;
  const int l16 = lane & 15, kq = lane >> 4;
  const __hip_bfloat16* msk = (*flag) ? mask_raw : mask;

  const f32x4 z = {0.f,0.f,0.f,0.f};
  for (int idx = tid; idx < 224*8; idx += 256) {
    int t = idx >> 3, c8 = idx & 7;
    f32x4 kv = z, vv = z;
    if (t < TGT) {
      kv = *(const f32x4*)(qkv + (rowbase + t)*QKV_N + EDIM   + h*HD + c8*8);
      vv = *(const f32x4*)(qkv + (rowbase + t)*QKV_N + 2*EDIM + h*HD + c8*8);
    }
    *(f32x4*)(lK + swz(t, c8*8)) = kv;
    *(f32x4*)(lV + swz(t, c8*8)) = vv;
  }

  int qr = q0 + wave*16 + l16;
  const int qrc = qr > TGT-1 ? TGT-1 : qr;
  s16x8 qf[2];
  #pragma unroll
  for (int kk = 0; kk < 2; ++kk)
    qf[kk] = *(const s16x8*)(qkv + (rowbase + qrc)*QKV_N + h*HD + kk*32 + kq*8);

  __syncthreads();

  f32x4 acc[14];
  #pragma unroll
  for (int nf = 0; nf < 14; ++nf) {
    acc[nf] = (f32x4){0.f,0.f,0.f,0.f};
    #pragma unroll
    for (int kk = 0; kk < 2; ++kk) {
      s16x8 kf = *(const s16x8*)(lK + swz(nf*16 + l16, kk*32 + kq*8));
      acc[nf] = __builtin_amdgcn_mfma_f32_16x16x32_bf16(kf, qf[kk], acc[nf], 0, 0, 0);
    }
  }

  float mx = -1e30f;
  #pragma unroll
  for (int nf = 0; nf < 14; ++nf) {
    #pragma unroll
    for (int r = 0; r < 4; ++r) {
      const int t = nf*16 + kq*4 + r;
      float s;
      if (t < TGT) s = acc[nf][r]*0.125f + bf2f(msk[(rowbase + qrc)*TGT + t]);
      else s = -1e30f;
      acc[nf][r] = s;
      mx = fmaxf(mx, s);
    }
  }
  mx = fmaxf(mx, __shfl_xor(mx, 16));
  mx = fmaxf(mx, __shfl_xor(mx, 32));

  float rs = 0.f;
  unsigned int pk[14][2];
  #pragma unroll
  for (int nf = 0; nf < 14; ++nf) {
    float p0 = __expf(acc[nf][0] - mx);
    float p1 = __expf(acc[nf][1] - mx);
    float p2 = __expf(acc[nf][2] - mx);
    float p3 = __expf(acc[nf][3] - mx);
    rs += (p0 + p1) + (p2 + p3);
    pk[nf][0] = packbf(p0, p1);
    pk[nf][1] = packbf(p2, p3);
  }
  rs += __shfl_xor(rs, 16);
  rs += __shfl_xor(rs, 32);

  f32x4 oacc[4];
  #pragma unroll
  for (int nf = 0; nf < 4; ++nf) oacc[nf] = (f32x4){0.f,0.f,0.f,0.f};

  const int slbase = l16 + ((kq & 1) << 5);
  #pragma unroll
  for (int kt = 0; kt < 7; ++kt) {
    s16x8 pa;
    #pragma unroll
    for (int jp = 0; jp < 4; ++jp) {
      const int srcLane = slbase + ((jp >> 1) << 4);
      int va = __shfl((int)pk[2*kt][jp & 1], srcLane, 64);
      int vb = __shfl((int)pk[2*kt + 1][jp & 1], srcLane, 64);
      int sel = (kq < 2) ? va : vb;
      pa[2*jp]     = (short)(sel & 0xffff);
      pa[2*jp + 1] = (short)(((unsigned int)sel) >> 16);
    }
    #pragma unroll
    for (int nf = 0; nf < 4; ++nf) {
      s16x8 vf;
      #pragma unroll
      for (int j = 0; j < 8; ++j) {
        const int t = kt*32 + kq*8 + j;
        vf[j] = *(const short*)(lV + swz(t, nf*16 + l16));
      }
      oacc[nf] = __builtin_amdgcn_mfma_f32_16x16x32_bf16(pa, vf, oacc[nf], 0, 0, 0);
    }
  }

  #pragma unroll
  for (int r = 0; r < 4; ++r) {
    const float rsrc = __shfl(rs, kq*4 + r, 64);
    const int qw = q0 + wave*16 + kq*4 + r;
    if (qw < TGT) {
      const float inv = 1.0f / rsrc;
      #pragma unroll
      for (int nf = 0; nf < 4; ++nf)
        xop[(rowbase + qw)*(size_t)EDIM + h*HD + nf*16 + l16] = f2bf(oacc[nf][r] * inv);
    }
  }
}

// ---------------- CLS grouped attention ----------------
__global__ __launch_bounds__(256) void cls_attn(
    const __hip_bfloat16* __restrict__ qkv,
    const __hip_bfloat16* __restrict__ mask,
    const __hip_bfloat16* __restrict__ mask_raw,
    const int* __restrict__ flag,
    const int* __restrict__ top_idx,
    __hip_bfloat16* __restrict__ Sg_all,
    __hip_bfloat16* __restrict__ x1buf)
{
  __shared__ __hip_bfloat16 lQ[16*64];
  __shared__ __hip_bfloat16 lV[256*64];
  __shared__ float red[16][17];
  __shared__ float rmax[16];
  __shared__ float rsum[16];

  const int tid = threadIdx.x;
  const int g = blockIdx.x / NH;
  const int h = blockIdx.x % NH;
  __hip_bfloat16* Sg = Sg_all + (size_t)blockIdx.x * 16 * KGP;
  const int wave = tid >> 6, lane = tid & 63;
  const int l16 = lane & 15, kq = lane >> 4, o4 = (lane >> 4) * 4;
  const __hip_bfloat16* msk = (*flag) ? mask_raw : mask;

  if (tid < 128) {
    int qi = tid >> 3, c8 = tid & 7;
    int ib = g*NF + qi;
    int top = top_idx[ib];
    f32x4 v = *(const f32x4*)(qkv + ((size_t)ib*TGT + top)*QKV_N + h*HD + c8*8);
    *(f32x4*)(lQ + qi*64 + c8*8) = v;
  }
  __syncthreads();

  s16x8 q8[2];
  #pragma unroll
  for (int kk = 0; kk < 2; ++kk)
    q8[kk] = *(const s16x8*)(lQ + l16*64 + kk*32 + kq*8);

  for (int nf = wave; nf < 208; nf += 4) {
    const int key = nf*16 + l16;
    if (nf < 197) {
      f32x4 a = {0.f,0.f,0.f,0.f};
      const size_t krow = (size_t)g*KG + key;
      #pragma unroll
      for (int kk = 0; kk < 2; ++kk) {
        s16x8 k8 = *(const s16x8*)(qkv + krow*QKV_N + EDIM + h*HD + kk*32 + kq*8);
        a = __builtin_amdgcn_mfma_f32_16x16x32_bf16(q8[kk], k8, a, 0, 0, 0);
      }
      const int f = key / 197;
      const int t = key - f*197;
      const float mval = bf2f(msk[((size_t)(g*NF + f)*TGT + (TGT-1))*TGT + t]);
      #pragma unroll
      for (int r = 0; r < 4; ++r)
        Sg[(o4 + r)*KGP + key] = f2bf(a[r]*0.125f + mval);
    } else {
      #pragma unroll
      for (int r = 0; r < 4; ++r)
        Sg[(o4 + r)*KGP + key] = f2bf(0.f);
    }
  }
  __syncthreads();

  {
    const int q = tid >> 4, c = tid & 15;
    float mx = -1e30f;
    for (int gch = c; gch < 394; gch += 16) {
      s16x8 sv = *(const s16x8*)(Sg + q*KGP + gch*8);
      #pragma unroll
      for (int j = 0; j < 8; ++j) mx = fmaxf(mx, b2f((unsigned short)sv[j]));
    }
    red[q][c] = mx;
    __syncthreads();
    if (tid < 16) {
      float m = red[tid][0];
      for (int j = 1; j < 16; ++j) m = fmaxf(m, red[tid][j]);
      rmax[tid] = m;
    }
    __syncthreads();
    const float rowmax = rmax[q];
    float sum = 0.f;
    for (int gch = c; gch < 394; gch += 16) {
      s16x8 sv = *(const s16x8*)(Sg + q*KGP + gch*8);
      s16x8 ov;
      #pragma unroll
      for (int jp = 0; jp < 4; ++jp) {
        float e0 = __expf(b2f((unsigned short)sv[2*jp])   - rowmax);
        float e1 = __expf(b2f((unsigned short)sv[2*jp+1]) - rowmax);
        sum += e0 + e1;
        unsigned int pr = packbf(e0, e1);
        ov[2*jp]   = (short)(pr & 0xffff);
        ov[2*jp+1] = (short)(pr >> 16);
      }
      *(s16x8*)(Sg + q*KGP + gch*8) = ov;
    }
    red[q][c] = sum;
    __syncthreads();
    if (tid < 16) {
      float s = 0.f;
      for (int j = 0; j < 16; ++j) s += red[tid][j];
      rsum[tid] = s;
    }
  }

  f32x4 oa = {0.f,0.f,0.f,0.f};
  const f32x4 z = {0.f,0.f,0.f,0.f};
  for (int ck = 0; ck < KGP; ck += 256) {
    __syncthreads();
    for (int idx = tid; idx < 256*8; idx += 256) {
      int t2 = idx >> 3, c8 = idx & 7;
      int key = ck + t2;
      f32x4 v = z;
      if (key < KG) v = *(const f32x4*)(qkv + ((size_t)g*KG + key)*QKV_N + 2*EDIM + h*HD + c8*8);
      *(f32x4*)(lV + swz(t2, c8*8)) = v;
    }
    __syncthreads();
    #pragma unroll
    for (int ks = 0; ks < 8; ++ks) {
      s16x8 pa = *(const s16x8*)(Sg + l16*KGP + ck + ks*32 + kq*8);
      s16x8 vf;
      #pragma unroll
      for (int j = 0; j < 8; ++j) {
        const int t2 = ks*32 + kq*8 + j;
        vf[j] = *(const short*)(lV + swz(t2, wave*16 + l16));
      }
      oa = __builtin_amdgcn_mfma_f32_16x16x32_bf16(pa, vf, oa, 0, 0, 0);
    }
  }
  #pragma unroll
  for (int r = 0; r < 4; ++r) {
    int q = o4 + r;
    int ib = g*NF + q;
    x1buf[(size_t)ib*EDIM + h*HD + wave*16 + l16] = f2bf(oa[r] / rsum[q]);
  }
}

// ---------------- LoRA head + CLS row update ----------------
__global__ __launch_bounds__(256) void final_update(
    void* __restrict__ out,
    const __hip_bfloat16* __restrict__ x1p,
    const __hip_bfloat16* __restrict__ dw, const __hip_bfloat16* __restrict__ db,
    const __hip_bfloat16* __restrict__ uw, const __hip_bfloat16* __restrict__ ub,
    const int* __restrict__ top_idx, const int* __restrict__ flag)
{
  __shared__ float x0[EDIM];
  __shared__ float hmid[64];
  const int i = blockIdx.x;
  const int tid = threadIdx.x;
  const int top = top_idx[i];
  const int isbf = *flag;
  const size_t rowoff = ((size_t)i*TGT + top)*EDIM;
  for (int e = tid; e < EDIM; e += 256)
    x0[e] = isbf ? bf2f(((const __hip_bfloat16*)out)[rowoff + e])
                 : ((const float*)out)[rowoff + e];
  __syncthreads();
  if (tid < 64) {
    float a = bf2f(db[tid]);
    for (int e = 0; e < EDIM; ++e) a += x0[e] * bf2f(dw[tid*EDIM + e]);
    hmid[tid] = a / (1.f + __expf(-1.702f * a));
  }
  __syncthreads();
  for (int e = tid; e < EDIM; e += 256) {
    float a = bf2f(ub[e]) + bf2f(x1p[(size_t)i*EDIM + e]);
    #pragma unroll
    for (int r = 0; r < 64; ++r) a += hmid[r] * bf2f(uw[e*64 + r]);
    if (isbf) ((__hip_bfloat16*)out)[rowoff + e] = f2bf(a);
    else ((float*)out)[rowoff + e] = a;
  }
}

extern "C" void kernel_launch(void* const* d_in, const int* in_sizes, int n_in,
                              void* d_out, int out_size, void* d_ws, size_t ws_size,
                              hipStream_t stream) {
  (void)in_sizes; (void)n_in; (void)out_size; (void)ws_size;
  const int* top_idx = (const int*)d_in[13];
  const __hip_bfloat16* x_raw    = (const __hip_bfloat16*)d_in[0];
  const __hip_bfloat16* mask_raw = (const __hip_bfloat16*)d_in[1];

  char* ws = (char*)d_ws;
  size_t off = 0;
  auto alloc = [&](size_t bytes) { char* p = ws + off; off += (bytes + 15) & ~(size_t)15; return p; };

  int* flag = (int*)alloc(16);
  __hip_bfloat16* x_c    = (__hip_bfloat16*)alloc((size_t)19365888*2);
  __hip_bfloat16* mask_c = (__hip_bfloat16*)alloc((size_t)4967552*2);
  __hip_bfloat16* wIn_c  = (__hip_bfloat16*)alloc((size_t)1769472*2);
  __hip_bfloat16* bIn_c  = (__hip_bfloat16*)alloc((size_t)2304*2);
  __hip_bfloat16* wOut_c = (__hip_bfloat16*)alloc((size_t)589824*2);
  __hip_bfloat16* bOut_c = (__hip_bfloat16*)alloc((size_t)768*2);
  __hip_bfloat16* la_c   = (__hip_bfloat16*)alloc((size_t)49152*2);
  __hip_bfloat16* lb_c   = (__hip_bfloat16*)alloc((size_t)147456*2);
  __hip_bfloat16* dw_c   = (__hip_bfloat16*)alloc((size_t)49152*2);
  __hip_bfloat16* db_c   = (__hip_bfloat16*)alloc((size_t)64*2);
  __hip_bfloat16* uw_c   = (__hip_bfloat16*)alloc((size_t)49152*2);
  __hip_bfloat16* ub_c   = (__hip_bfloat16*)alloc((size_t)768*2);
  __hip_bfloat16* Wc     = (__hip_bfloat16*)alloc((size_t)QKV_N*EDIM*2);
  __hip_bfloat16* qkv    = (__hip_bfloat16*)alloc((size_t)M_TOT*QKV_N*2);
  __hip_bfloat16* xop    = (__hip_bfloat16*)alloc((size_t)M_TOT*EDIM*2);
  __hip_bfloat16* x1b    = (__hip_bfloat16*)alloc((size_t)BSZ*EDIM*2);
  __hip_bfloat16* x1p    = (__hip_bfloat16*)alloc((size_t)BSZ*EDIM*2);
  __hip_bfloat16* Sg     = (__hip_bfloat16*)alloc((size_t)96*16*KGP*2);

  detect_dtype<<<1, 64, 0, stream>>>((const unsigned short*)d_in[0], flag);

  auto CV = [&](int idx, __hip_bfloat16* dst, int n, int skip) {
    int n8 = n / 8;
    int grid = (n8 + 255) / 256; if (grid > 2048) grid = 2048; if (grid < 1) grid = 1;
    convert_bf16<<<grid, 256, 0, stream>>>(d_in[idx], dst, n8, flag, skip);
  };
  CV(0,  x_c,    19365888, 1);
  CV(1,  mask_c, 4967552, 1);
  CV(2,  wIn_c,  1769472, 0);
  CV(3,  bIn_c,  2304, 0);
  CV(4,  wOut_c, 589824, 0);
  CV(5,  bOut_c, 768, 0);
  CV(6,  la_c,   49152, 0);
  CV(7,  lb_c,   147456, 0);
  CV(8,  dw_c,   49152, 0);
  CV(9,  db_c,   64, 0);
  CV(10, uw_c,   49152, 0);
  CV(11, ub_c,   768, 0);

  build_wc<<<2304, 256, 0, stream>>>(wIn_c, la_c, lb_c, Wc);

  // qkv: M=25216 -> 99 m-tiles, N=2304 -> 9 n-tiles
  gemm_bt_8ph<<<99*9, 512, 0, stream>>>(x_c, x_raw, Wc, bIn_c, qkv,
                                        M_TOT, QKV_N, EDIM, 9, flag, 0);
  attn_fused<<<dim3(6144), 256, 0, stream>>>(qkv, mask_c, mask_raw, flag, xop);
  // out-proj: N=768 -> 3 n-tiles
  gemm_bt_8ph<<<99*3, 512, 0, stream>>>(xop, xop, wOut_c, bOut_c, d_out,
                                        M_TOT, EDIM, EDIM, 3, flag, 1);
  cls_attn<<<dim3(96), 256, 0, stream>>>(qkv, mask_c, mask_raw, flag, top_idx, Sg, x1b);
  gemm_bt_8ph<<<1*3, 512, 0, stream>>>(x1b, x1b, wOut_c, bOut_c, x1p,
                                       BSZ, EDIM, EDIM, 3, flag, 0);
  final_update<<<128, 256, 0, stream>>>(d_out, x1p, dw_c, db_c, uw_c, ub_c, top_idx, flag);
}

// Round 8
// 569.356 us; speedup vs baseline: 2.0467x; 1.0605x over previous
//
#include <hip/hip_runtime.h>
#include <hip/hip_bf16.h>

typedef __attribute__((ext_vector_type(4))) float f32x4;
typedef __attribute__((ext_vector_type(8))) short s16x8;

#define BSZ 128
#define TGT 197
#define EDIM 768
#define NH 12
#define HD 64
#define NF 16
#define M_TOT (BSZ*TGT)      // 25216
#define QKV_N (3*EDIM)       // 2304
#define KG (NF*TGT)          // 3152
#define KGP 3328
#define VSTR 264             // V^T row stride: >=256 for XOR range, !=0 mod 128B for banks

__device__ __forceinline__ float b2f(unsigned short u) {
  return __uint_as_float(((unsigned int)u) << 16);
}
__device__ __forceinline__ float bf2f(__hip_bfloat16 b) { return __bfloat162float(b); }
__device__ __forceinline__ __hip_bfloat16 f2bf(float f) { return __float2bfloat16(f); }
__device__ __forceinline__ unsigned int packbf(float a, float b) {
  __hip_bfloat16 x = __float2bfloat16(a), y = __float2bfloat16(b);
  return (unsigned int)*(unsigned short*)&x | ((unsigned int)*(unsigned short*)&y << 16);
}
// swizzled short-index into a [T][64] bf16 LDS tile (cls kernel)
__device__ __forceinline__ int swz(int t, int c) {
  return t*64 + (c ^ ((((t & 7) ^ ((t >> 3) & 3))) << 3));
}
// V^T tile [64 d][VSTR t]: XOR keeps b128 t-contiguity (bits 3-5 only);
// stride 264 (528 B = 4 banks mod 32) makes both transpose-writes and
// per-d b128 reads 2-way (free). tx <= 255 < 264: in-bounds.
__device__ __forceinline__ int vswz(int d, int t) {
  return d*VSTR + (t ^ (d & 56));
}

__device__ __forceinline__ void gload_lds16(const void* gsrc, void* ldst) {
  __builtin_amdgcn_global_load_lds(
      (const __attribute__((address_space(1))) unsigned int*)gsrc,
      (__attribute__((address_space(3))) unsigned int*)ldst, 16, 0, 0);
}

// ---------------- dtype detection (+ init mask-zero flag to 1) ----------------
__global__ void detect_dtype(const unsigned short* __restrict__ xraw,
                             int* __restrict__ flag, int* __restrict__ mz) {
  if (threadIdx.x == 0 && blockIdx.x == 0) {
    float mx = 0.f;
    for (int j = 0; j < 1024; ++j) {
      float v = fabsf(b2f(xraw[j]));
      if (v < 1e30f) mx = fmaxf(mx, v);
      else mx = 1e30f;
    }
    *flag = (mx < 100.0f) ? 1 : 0;
    *mz = 1;
  }
}

// ---------------- mask-zero detection: mz stays 1 iff mask == +-0 everywhere --------
__global__ __launch_bounds__(256) void detect_mask_zero(
    const unsigned int* __restrict__ mraw, int nelem,
    const int* __restrict__ flag, int* __restrict__ mz)
{
  const int isbf = *flag;
  const int nwords = isbf ? (nelem >> 1) : nelem;
  const unsigned int am = isbf ? 0x7fff7fffu : 0x7fffffffu;
  unsigned int acc = 0;
  for (int i = blockIdx.x*256 + threadIdx.x; i < nwords; i += gridDim.x*256)
    acc |= (mraw[i] & am);
  if (acc) atomicAnd(mz, 0);
}

// ---------------- canonicalize float tensor to bf16 ----------------
__global__ __launch_bounds__(256) void convert_bf16(
    const void* __restrict__ src, __hip_bfloat16* __restrict__ dst,
    int n8, const int* __restrict__ flag, int skip_if_bf)
{
  const int isbf = *flag;
  if (skip_if_bf && isbf) return;
  int i = blockIdx.x * 256 + threadIdx.x;
  const int stride = gridDim.x * 256;
  if (isbf) {
    const s16x8* s = (const s16x8*)src;
    s16x8* d = (s16x8*)dst;
    for (; i < n8; i += stride) d[i] = s[i];
  } else {
    const f32x4* s = (const f32x4*)src;
    s16x8* d = (s16x8*)dst;
    for (; i < n8; i += stride) {
      f32x4 a = s[i*2], b = s[i*2+1];
      s16x8 o;
      #pragma unroll
      for (int j = 0; j < 4; ++j) { __hip_bfloat16 t = f2bf(a[j]); o[j] = *(short*)&t; }
      #pragma unroll
      for (int j = 0; j < 4; ++j) { __hip_bfloat16 t = f2bf(b[j]); o[4+j] = *(short*)&t; }
      d[i] = o;
    }
  }
}

// ---------------- Wc = in_proj_weight + lora_b @ lora_a ----------------
__global__ __launch_bounds__(256) void build_wc(
    const __hip_bfloat16* __restrict__ W,
    const __hip_bfloat16* __restrict__ la,
    const __hip_bfloat16* __restrict__ lb,
    __hip_bfloat16* __restrict__ Wc)
{
  __shared__ float lbr[64];
  const int n = blockIdx.x;
  if (threadIdx.x < 64) lbr[threadIdx.x] = bf2f(lb[n*64 + threadIdx.x]);
  __syncthreads();
  for (int e = threadIdx.x; e < EDIM; e += 256) {
    float acc = bf2f(W[(size_t)n*EDIM + e]);
    for (int r = 0; r < 64; ++r) acc += lbr[r] * bf2f(la[r*EDIM + e]);
    Wc[(size_t)n*EDIM + e] = f2bf(acc);
  }
}

// ---------------- 256x256 8-phase GEMM: C = A[M][K] @ B[N][K]^T + bias ----------------
__global__ __launch_bounds__(512) void gemm_bt_8ph(
    const __hip_bfloat16* __restrict__ A,
    const __hip_bfloat16* __restrict__ A_alt,
    const __hip_bfloat16* __restrict__ B,
    const __hip_bfloat16* __restrict__ bias,
    void* __restrict__ C,
    int M, int N, int K, int ntiles,
    const int* __restrict__ flag, int flag_mode)
{
  __shared__ char lds[131072];
  const int tid = threadIdx.x;
  const int wave = tid >> 6, lane = tid & 63;
  const int l16 = lane & 15, kq = lane >> 4;
  const int wr = wave >> 2, wc2 = wave & 3;

  const int nwg = gridDim.x;
  const int bid = blockIdx.x;
  const int qc = nwg >> 3, rc = nwg & 7;
  const int xcd = bid & 7;
  const int wgid = (xcd < rc ? xcd*(qc+1) : rc*(qc+1) + (xcd-rc)*qc) + (bid >> 3);
  const long brow = (long)(wgid / ntiles) * 256;
  const long bcol = (long)(wgid % ntiles) * 256;

  const int isbf = *flag;
  const __hip_bfloat16* Ause = isbf ? A_alt : A;
  const int nkt = K >> 6;

  const int srow = tid >> 3;
  const int schunk = tid & 7;
  const int wuni = wave << 10;

  auto stA = [&](int t, int buf, int issue) {
    int ar = issue*64 + srow;
    int cs = schunk ^ (ar & 7);
    long gr = brow + ar; if (gr > (long)M - 1) gr = M - 1;
    gload_lds16(Ause + gr*(long)K + t*64 + cs*8,
                lds + buf*65536 + issue*8192 + wuni);
  };
  auto stB = [&](int t, int buf, int issue) {
    int br = issue*64 + srow;
    int cs = schunk ^ (br & 7);
    gload_lds16(B + (bcol + br)*(long)K + t*64 + cs*8,
                lds + buf*65536 + 32768 + issue*8192 + wuni);
  };
  auto rdA = [&](int buf, int q, int a, int ks) -> s16x8 {
    int ar = wr*128 + q*32 + a*16 + l16;
    int ch = ks*4 + kq;
    return *(const s16x8*)(lds + buf*65536 + ar*128 + ((ch ^ (ar & 7)) << 4));
  };
  auto rdB = [&](int buf, int ni, int ks) -> s16x8 {
    int br = wc2*64 + ni*16 + l16;
    int ch = ks*4 + kq;
    return *(const s16x8*)(lds + buf*65536 + 32768 + br*128 + ((ch ^ (br & 7)) << 4));
  };

  f32x4 acc[8][4];
  #pragma unroll
  for (int i = 0; i < 8; ++i)
    #pragma unroll
    for (int j = 0; j < 4; ++j) acc[i][j] = (f32x4){0.f,0.f,0.f,0.f};

  stB(0,0,0); stB(0,0,1); stB(0,0,2); stB(0,0,3);
  stA(0,0,0); stA(0,0,2); stA(0,0,1); stA(0,0,3);
  asm volatile("s_waitcnt vmcnt(2)" ::: "memory");
  __builtin_amdgcn_s_barrier();

  for (int t = 0; t < nkt; ++t) {
    const int cur = t & 1, nxt = cur ^ 1;
    const bool pf = (t + 1 < nkt);
    s16x8 bfr[4][2], af[2][2];

    #pragma unroll
    for (int ni = 0; ni < 4; ++ni) { bfr[ni][0] = rdB(cur,ni,0); bfr[ni][1] = rdB(cur,ni,1); }
    af[0][0]=rdA(cur,0,0,0); af[0][1]=rdA(cur,0,0,1);
    af[1][0]=rdA(cur,0,1,0); af[1][1]=rdA(cur,0,1,1);
    if (pf) { stB(t+1,nxt,0); stB(t+1,nxt,1); }
    __builtin_amdgcn_s_barrier();
    asm volatile("s_waitcnt lgkmcnt(0)" ::: "memory");
    __builtin_amdgcn_sched_barrier(0);
    __builtin_amdgcn_s_setprio(1);
    #pragma unroll
    for (int ks = 0; ks < 2; ++ks)
      #pragma unroll
      for (int ni = 0; ni < 4; ++ni) {
        acc[0][ni] = __builtin_amdgcn_mfma_f32_16x16x32_bf16(af[0][ks], bfr[ni][ks], acc[0][ni], 0,0,0);
        acc[1][ni] = __builtin_amdgcn_mfma_f32_16x16x32_bf16(af[1][ks], bfr[ni][ks], acc[1][ni], 0,0,0);
      }
    __builtin_amdgcn_s_setprio(0);

    af[0][0]=rdA(cur,1,0,0); af[0][1]=rdA(cur,1,0,1);
    af[1][0]=rdA(cur,1,1,0); af[1][1]=rdA(cur,1,1,1);
    if (pf) {
      stB(t+1,nxt,2); stB(t+1,nxt,3);
      asm volatile("s_waitcnt vmcnt(4)" ::: "memory");
    } else {
      asm volatile("s_waitcnt vmcnt(0)" ::: "memory");
    }
    __builtin_amdgcn_s_barrier();
    asm volatile("s_waitcnt lgkmcnt(0)" ::: "memory");
    __builtin_amdgcn_sched_barrier(0);
    __builtin_amdgcn_s_setprio(1);
    #pragma unroll
    for (int ks = 0; ks < 2; ++ks)
      #pragma unroll
      for (int ni = 0; ni < 4; ++ni) {
        acc[2][ni] = __builtin_amdgcn_mfma_f32_16x16x32_bf16(af[0][ks], bfr[ni][ks], acc[2][ni], 0,0,0);
        acc[3][ni] = __builtin_amdgcn_mfma_f32_16x16x32_bf16(af[1][ks], bfr[ni][ks], acc[3][ni], 0,0,0);
      }
    __builtin_amdgcn_s_setprio(0);

    af[0][0]=rdA(cur,2,0,0); af[0][1]=rdA(cur,2,0,1);
    af[1][0]=rdA(cur,2,1,0); af[1][1]=rdA(cur,2,1,1);
    if (pf) { stA(t+1,nxt,0); stA(t+1,nxt,2); }
    __builtin_amdgcn_s_barrier();
    asm volatile("s_waitcnt lgkmcnt(0)" ::: "memory");
    __builtin_amdgcn_sched_barrier(0);
    __builtin_amdgcn_s_setprio(1);
    #pragma unroll
    for (int ks = 0; ks < 2; ++ks)
      #pragma unroll
      for (int ni = 0; ni < 4; ++ni) {
        acc[4][ni] = __builtin_amdgcn_mfma_f32_16x16x32_bf16(af[0][ks], bfr[ni][ks], acc[4][ni], 0,0,0);
        acc[5][ni] = __builtin_amdgcn_mfma_f32_16x16x32_bf16(af[1][ks], bfr[ni][ks], acc[5][ni], 0,0,0);
      }
    __builtin_amdgcn_s_setprio(0);

    af[0][0]=rdA(cur,3,0,0); af[0][1]=rdA(cur,3,0,1);
    af[1][0]=rdA(cur,3,1,0); af[1][1]=rdA(cur,3,1,1);
    if (pf) { stA(t+1,nxt,1); stA(t+1,nxt,3); }
    asm volatile("s_waitcnt vmcnt(2)" ::: "memory");
    __builtin_amdgcn_s_barrier();
    asm volatile("s_waitcnt lgkmcnt(0)" ::: "memory");
    __builtin_amdgcn_sched_barrier(0);
    __builtin_amdgcn_s_setprio(1);
    #pragma unroll
    for (int ks = 0; ks < 2; ++ks)
      #pragma unroll
      for (int ni = 0; ni < 4; ++ni) {
        acc[6][ni] = __builtin_amdgcn_mfma_f32_16x16x32_bf16(af[0][ks], bfr[ni][ks], acc[6][ni], 0,0,0);
        acc[7][ni] = __builtin_amdgcn_mfma_f32_16x16x32_bf16(af[1][ks], bfr[ni][ks], acc[7][ni], 0,0,0);
      }
    __builtin_amdgcn_s_setprio(0);
  }

  __builtin_amdgcn_s_barrier();

  const int f32o = flag_mode && (!isbf);
  float bv[4];
  #pragma unroll
  for (int ni = 0; ni < 4; ++ni) bv[ni] = bf2f(bias[bcol + wc2*64 + ni*16 + l16]);
  const int o4 = kq*4;

  if (!f32o) {
    __hip_bfloat16* eb = (__hip_bfloat16*)(lds + wave*2048);
    __hip_bfloat16* Cb = (__hip_bfloat16*)C;
    const int rr = lane >> 3, cg = lane & 7;
    #pragma unroll
    for (int mi = 0; mi < 8; ++mi) {
      #pragma unroll
      for (int ni = 0; ni < 4; ++ni)
        #pragma unroll
        for (int r = 0; r < 4; ++r) {
          const int row16 = o4 + r;
          const int sidx = row16*64 + ((((ni*2 + (l16 >> 3)) ^ (row16 & 7)) << 3) | (l16 & 7));
          eb[sidx] = f2bf(acc[mi][ni][r] + bv[ni]);
        }
      asm volatile("s_waitcnt lgkmcnt(0)" ::: "memory");
      __builtin_amdgcn_sched_barrier(0);
      #pragma unroll
      for (int pass = 0; pass < 2; ++pass) {
        const int row16 = pass*8 + rr;
        const long grow = brow + wr*128 + mi*16 + row16;
        if (grow < M) {
          s16x8 v = *(const s16x8*)(eb + row16*64 + ((cg ^ (row16 & 7)) << 3));
          *(s16x8*)(Cb + grow*(long)N + bcol + wc2*64 + cg*8) = v;
        }
      }
      asm volatile("s_waitcnt lgkmcnt(0)" ::: "memory");
      __builtin_amdgcn_sched_barrier(0);
    }
  } else {
    #pragma unroll
    for (int mi = 0; mi < 8; ++mi)
      #pragma unroll
      for (int ni = 0; ni < 4; ++ni)
        #pragma unroll
        for (int r = 0; r < 4; ++r) {
          const long grow = brow + wr*128 + mi*16 + o4 + r;
          if (grow < M)
            ((float*)C)[grow*(long)N + bcol + wc2*64 + ni*16 + l16] = acc[mi][ni][r] + bv[ni];
        }
  }
}

// ---------------- fused attention: V^T-only LDS, K direct from global (L2-hot) ------
__global__ __launch_bounds__(256) void attn_fused(
    const __hip_bfloat16* __restrict__ qkv,
    const __hip_bfloat16* __restrict__ mask,
    const __hip_bfloat16* __restrict__ mask_raw,
    const int* __restrict__ flag,
    const int* __restrict__ mzp,
    __hip_bfloat16* __restrict__ xop)
{
  __shared__ __hip_bfloat16 lVt[64*VSTR];   // 33 KB

  const int tid = threadIdx.x;
  const int blk = blockIdx.x;
  const int xcd = blk & 7;
  const int slot = blk >> 3;
  const int ih = xcd * 192 + (slot >> 2);
  const int qt = slot & 3;
  const int h = ih % NH;
  const int i = ih / NH;
  const int q0 = qt * 64;
  const size_t rowbase = (size_t)i * TGT;
  const int wave = tid >> 6, lane = tid & 63;
  const int l16 = lane & 15, kq = lane >> 4;
  const int mz = *mzp;
  const __hip_bfloat16* msk = (*flag) ? mask_raw : mask;

  // ---- Q fragments first (hide latency under V^T staging) ----
  int qr = q0 + wave*16 + l16;
  const int qrc = qr > TGT-1 ? TGT-1 : qr;
  s16x8 qf[2];
  #pragma unroll
  for (int kk = 0; kk < 2; ++kk)
    qf[kk] = *(const s16x8*)(qkv + (rowbase + qrc)*QKV_N + h*HD + kk*32 + kq*8);

  // ---- stage V^T [64 d][t], swizzled transpose; zero pad t in [197,224) ----
  const f32x4 z = {0.f,0.f,0.f,0.f};
  for (int idx = tid; idx < 224*8; idx += 256) {
    int t = idx >> 3, c8 = idx & 7;
    f32x4 vv = z;
    if (t < TGT) vv = *(const f32x4*)(qkv + (rowbase + t)*QKV_N + 2*EDIM + h*HD + c8*8);
    const __hip_bfloat16* pv = (const __hip_bfloat16*)&vv;
    const int tx = t ^ (c8 << 3);     // (d & 56) == c8<<3 for d = c8*8 + j
    #pragma unroll
    for (int j = 0; j < 8; ++j)
      lVt[(c8*8 + j)*VSTR + tx] = pv[j];
  }
  __syncthreads();   // the only barrier

  // ---- S^T = mfma(K, Q), K fragments straight from global ----
  f32x4 acc[14];
  #pragma unroll
  for (int nf = 0; nf < 14; ++nf) {
    int trow = nf*16 + l16; if (trow > TGT-1) trow = TGT-1;
    acc[nf] = (f32x4){0.f,0.f,0.f,0.f};
    #pragma unroll
    for (int kk = 0; kk < 2; ++kk) {
      s16x8 kf = *(const s16x8*)(qkv + (rowbase + trow)*QKV_N + EDIM + h*HD + kk*32 + kq*8);
      acc[nf] = __builtin_amdgcn_mfma_f32_16x16x32_bf16(kf, qf[kk], acc[nf], 0, 0, 0);
    }
  }

  float mx = -1e30f;
  #pragma unroll
  for (int nf = 0; nf < 14; ++nf) {
    #pragma unroll
    for (int r = 0; r < 4; ++r) {
      const int t = nf*16 + kq*4 + r;
      float s;
      if (t < TGT) {
        s = acc[nf][r]*0.125f;
        if (!mz) s += bf2f(msk[(rowbase + qrc)*TGT + t]);
      } else s = -1e30f;
      acc[nf][r] = s;
      mx = fmaxf(mx, s);
    }
  }
  mx = fmaxf(mx, __shfl_xor(mx, 16));
  mx = fmaxf(mx, __shfl_xor(mx, 32));

  float rs = 0.f;
  unsigned int pk[14][2];
  #pragma unroll
  for (int nf = 0; nf < 14; ++nf) {
    float p0 = __expf(acc[nf][0] - mx);
    float p1 = __expf(acc[nf][1] - mx);
    float p2 = __expf(acc[nf][2] - mx);
    float p3 = __expf(acc[nf][3] - mx);
    rs += (p0 + p1) + (p2 + p3);
    pk[nf][0] = packbf(p0, p1);
    pk[nf][1] = packbf(p2, p3);
  }
  rs += __shfl_xor(rs, 16);
  rs += __shfl_xor(rs, 32);

  f32x4 oacc[4];
  #pragma unroll
  for (int nf = 0; nf < 4; ++nf) oacc[nf] = (f32x4){0.f,0.f,0.f,0.f};

  const int slbase = l16 + ((kq & 1) << 5);
  #pragma unroll
  for (int kt = 0; kt < 7; ++kt) {
    s16x8 pa;
    #pragma unroll
    for (int jp = 0; jp < 4; ++jp) {
      const int srcLane = slbase + ((jp >> 1) << 4);
      int va = __shfl((int)pk[2*kt][jp & 1], srcLane, 64);
      int vb = __shfl((int)pk[2*kt + 1][jp & 1], srcLane, 64);
      int sel = (kq < 2) ? va : vb;
      pa[2*jp]     = (short)(sel & 0xffff);
      pa[2*jp + 1] = (short)(((unsigned int)sel) >> 16);
    }
    #pragma unroll
    for (int nf = 0; nf < 4; ++nf) {
      s16x8 vf = *(const s16x8*)(lVt + vswz(nf*16 + l16, kt*32 + kq*8));
      oacc[nf] = __builtin_amdgcn_mfma_f32_16x16x32_bf16(pa, vf, oacc[nf], 0, 0, 0);
    }
  }

  #pragma unroll
  for (int r = 0; r < 4; ++r) {
    const float rsrc = __shfl(rs, kq*4 + r, 64);
    const int qw = q0 + wave*16 + kq*4 + r;
    if (qw < TGT) {
      const float inv = 1.0f / rsrc;
      #pragma unroll
      for (int nf = 0; nf < 4; ++nf)
        xop[(rowbase + qw)*(size_t)EDIM + h*HD + nf*16 + l16] = f2bf(oacc[nf][r] * inv);
    }
  }
}

// ---------------- CLS grouped attention ----------------
__global__ __launch_bounds__(256) void cls_attn(
    const __hip_bfloat16* __restrict__ qkv,
    const __hip_bfloat16* __restrict__ mask,
    const __hip_bfloat16* __restrict__ mask_raw,
    const int* __restrict__ flag,
    const int* __restrict__ mzp,
    const int* __restrict__ top_idx,
    __hip_bfloat16* __restrict__ Sg_all,
    __hip_bfloat16* __restrict__ x1buf)
{
  __shared__ __hip_bfloat16 lQ[16*64];
  __shared__ __hip_bfloat16 lV[256*64];
  __shared__ float red[16][17];
  __shared__ float rmax[16];
  __shared__ float rsum[16];

  const int tid = threadIdx.x;
  const int g = blockIdx.x / NH;
  const int h = blockIdx.x % NH;
  __hip_bfloat16* Sg = Sg_all + (size_t)blockIdx.x * 16 * KGP;
  const int wave = tid >> 6, lane = tid & 63;
  const int l16 = lane & 15, kq = lane >> 4, o4 = (lane >> 4) * 4;
  const int mz = *mzp;
  const __hip_bfloat16* msk = (*flag) ? mask_raw : mask;

  if (tid < 128) {
    int qi = tid >> 3, c8 = tid & 7;
    int ib = g*NF + qi;
    int top = top_idx[ib];
    f32x4 v = *(const f32x4*)(qkv + ((size_t)ib*TGT + top)*QKV_N + h*HD + c8*8);
    *(f32x4*)(lQ + qi*64 + c8*8) = v;
  }
  __syncthreads();

  s16x8 q8[2];
  #pragma unroll
  for (int kk = 0; kk < 2; ++kk)
    q8[kk] = *(const s16x8*)(lQ + l16*64 + kk*32 + kq*8);

  for (int nf = wave; nf < 208; nf += 4) {
    const int key = nf*16 + l16;
    if (nf < 197) {
      f32x4 a = {0.f,0.f,0.f,0.f};
      const size_t krow = (size_t)g*KG + key;
      #pragma unroll
      for (int kk = 0; kk < 2; ++kk) {
        s16x8 k8 = *(const s16x8*)(qkv + krow*QKV_N + EDIM + h*HD + kk*32 + kq*8);
        a = __builtin_amdgcn_mfma_f32_16x16x32_bf16(q8[kk], k8, a, 0, 0, 0);
      }
      float mval = 0.f;
      if (!mz) {
        const int f = key / 197;
        const int t = key - f*197;
        mval = bf2f(msk[((size_t)(g*NF + f)*TGT + (TGT-1))*TGT + t]);
      }
      #pragma unroll
      for (int r = 0; r < 4; ++r)
        Sg[(o4 + r)*KGP + key] = f2bf(a[r]*0.125f + mval);
    } else {
      #pragma unroll
      for (int r = 0; r < 4; ++r)
        Sg[(o4 + r)*KGP + key] = f2bf(0.f);
    }
  }
  __syncthreads();

  {
    const int q = tid >> 4, c = tid & 15;
    float mx = -1e30f;
    for (int gch = c; gch < 394; gch += 16) {
      s16x8 sv = *(const s16x8*)(Sg + q*KGP + gch*8);
      #pragma unroll
      for (int j = 0; j < 8; ++j) mx = fmaxf(mx, b2f((unsigned short)sv[j]));
    }
    red[q][c] = mx;
    __syncthreads();
    if (tid < 16) {
      float m = red[tid][0];
      for (int j = 1; j < 16; ++j) m = fmaxf(m, red[tid][j]);
      rmax[tid] = m;
    }
    __syncthreads();
    const float rowmax = rmax[q];
    float sum = 0.f;
    for (int gch = c; gch < 394; gch += 16) {
      s16x8 sv = *(const s16x8*)(Sg + q*KGP + gch*8);
      s16x8 ov;
      #pragma unroll
      for (int jp = 0; jp < 4; ++jp) {
        float e0 = __expf(b2f((unsigned short)sv[2*jp])   - rowmax);
        float e1 = __expf(b2f((unsigned short)sv[2*jp+1]) - rowmax);
        sum += e0 + e1;
        unsigned int pr = packbf(e0, e1);
        ov[2*jp]   = (short)(pr & 0xffff);
        ov[2*jp+1] = (short)(pr >> 16);
      }
      *(s16x8*)(Sg + q*KGP + gch*8) = ov;
    }
    red[q][c] = sum;
    __syncthreads();
    if (tid < 16) {
      float s = 0.f;
      for (int j = 0; j < 16; ++j) s += red[tid][j];
      rsum[tid] = s;
    }
  }

  f32x4 oa = {0.f,0.f,0.f,0.f};
  const f32x4 z = {0.f,0.f,0.f,0.f};
  for (int ck = 0; ck < KGP; ck += 256) {
    __syncthreads();
    for (int idx = tid; idx < 256*8; idx += 256) {
      int t2 = idx >> 3, c8 = idx & 7;
      int key = ck + t2;
      f32x4 v = z;
      if (key < KG) v = *(const f32x4*)(qkv + ((size_t)g*KG + key)*QKV_N + 2*EDIM + h*HD + c8*8);
      *(f32x4*)(lV + swz(t2, c8*8)) = v;
    }
    __syncthreads();
    #pragma unroll
    for (int ks = 0; ks < 8; ++ks) {
      s16x8 pa = *(const s16x8*)(Sg + l16*KGP + ck + ks*32 + kq*8);
      s16x8 vf;
      #pragma unroll
      for (int j = 0; j < 8; ++j) {
        const int t2 = ks*32 + kq*8 + j;
        vf[j] = *(const short*)(lV + swz(t2, wave*16 + l16));
      }
      oa = __builtin_amdgcn_mfma_f32_16x16x32_bf16(pa, vf, oa, 0, 0, 0);
    }
  }
  #pragma unroll
  for (int r = 0; r < 4; ++r) {
    int q = o4 + r;
    int ib = g*NF + q;
    x1buf[(size_t)ib*EDIM + h*HD + wave*16 + l16] = f2bf(oa[r] / rsum[q]);
  }
}

// ---------------- LoRA head + CLS row update ----------------
__global__ __launch_bounds__(256) void final_update(
    void* __restrict__ out,
    const __hip_bfloat16* __restrict__ x1p,
    const __hip_bfloat16* __restrict__ dw, const __hip_bfloat16* __restrict__ db,
    const __hip_bfloat16* __restrict__ uw, const __hip_bfloat16* __restrict__ ub,
    const int* __restrict__ top_idx, const int* __restrict__ flag)
{
  __shared__ float x0[EDIM];
  __shared__ float hmid[64];
  const int i = blockIdx.x;
  const int tid = threadIdx.x;
  const int top = top_idx[i];
  const int isbf = *flag;
  const size_t rowoff = ((size_t)i*TGT + top)*EDIM;
  for (int e = tid; e < EDIM; e += 256)
    x0[e] = isbf ? bf2f(((const __hip_bfloat16*)out)[rowoff + e])
                 : ((const float*)out)[rowoff + e];
  __syncthreads();
  if (tid < 64) {
    float a = bf2f(db[tid]);
    for (int e = 0; e < EDIM; ++e) a += x0[e] * bf2f(dw[tid*EDIM + e]);
    hmid[tid] = a / (1.f + __expf(-1.702f * a));
  }
  __syncthreads();
  for (int e = tid; e < EDIM; e += 256) {
    float a = bf2f(ub[e]) + bf2f(x1p[(size_t)i*EDIM + e]);
    #pragma unroll
    for (int r = 0; r < 64; ++r) a += hmid[r] * bf2f(uw[e*64 + r]);
    if (isbf) ((__hip_bfloat16*)out)[rowoff + e] = f2bf(a);
    else ((float*)out)[rowoff + e] = a;
  }
}

extern "C" void kernel_launch(void* const* d_in, const int* in_sizes, int n_in,
                              void* d_out, int out_size, void* d_ws, size_t ws_size,
                              hipStream_t stream) {
  (void)in_sizes; (void)n_in; (void)out_size; (void)ws_size;
  const int* top_idx = (const int*)d_in[13];
  const __hip_bfloat16* x_raw    = (const __hip_bfloat16*)d_in[0];
  const __hip_bfloat16* mask_raw = (const __hip_bfloat16*)d_in[1];

  char* ws = (char*)d_ws;
  size_t off = 0;
  auto alloc = [&](size_t bytes) { char* p = ws + off; off += (bytes + 15) & ~(size_t)15; return p; };

  int* flag = (int*)alloc(16);
  int* mz   = (int*)alloc(16);
  __hip_bfloat16* x_c    = (__hip_bfloat16*)alloc((size_t)19365888*2);
  __hip_bfloat16* mask_c = (__hip_bfloat16*)alloc((size_t)4967552*2);
  __hip_bfloat16* wIn_c  = (__hip_bfloat16*)alloc((size_t)1769472*2);
  __hip_bfloat16* bIn_c  = (__hip_bfloat16*)alloc((size_t)2304*2);
  __hip_bfloat16* wOut_c = (__hip_bfloat16*)alloc((size_t)589824*2);
  __hip_bfloat16* bOut_c = (__hip_bfloat16*)alloc((size_t)768*2);
  __hip_bfloat16* la_c   = (__hip_bfloat16*)alloc((size_t)49152*2);
  __hip_bfloat16* lb_c   = (__hip_bfloat16*)alloc((size_t)147456*2);
  __hip_bfloat16* dw_c   = (__hip_bfloat16*)alloc((size_t)49152*2);
  __hip_bfloat16* db_c   = (__hip_bfloat16*)alloc((size_t)64*2);
  __hip_bfloat16* uw_c   = (__hip_bfloat16*)alloc((size_t)49152*2);
  __hip_bfloat16* ub_c   = (__hip_bfloat16*)alloc((size_t)768*2);
  __hip_bfloat16* Wc     = (__hip_bfloat16*)alloc((size_t)QKV_N*EDIM*2);
  __hip_bfloat16* qkv    = (__hip_bfloat16*)alloc((size_t)M_TOT*QKV_N*2);
  __hip_bfloat16* xop    = (__hip_bfloat16*)alloc((size_t)M_TOT*EDIM*2);
  __hip_bfloat16* x1b    = (__hip_bfloat16*)alloc((size_t)BSZ*EDIM*2);
  __hip_bfloat16* x1p    = (__hip_bfloat16*)alloc((size_t)BSZ*EDIM*2);
  __hip_bfloat16* Sg     = (__hip_bfloat16*)alloc((size_t)96*16*KGP*2);

  detect_dtype<<<1, 64, 0, stream>>>((const unsigned short*)d_in[0], flag, mz);
  detect_mask_zero<<<2048, 256, 0, stream>>>((const unsigned int*)d_in[1], 4967552, flag, mz);

  auto CV = [&](int idx, __hip_bfloat16* dst, int n, int skip) {
    int n8 = n / 8;
    int grid = (n8 + 255) / 256; if (grid > 2048) grid = 2048; if (grid < 1) grid = 1;
    convert_bf16<<<grid, 256, 0, stream>>>(d_in[idx], dst, n8, flag, skip);
  };
  CV(0,  x_c,    19365888, 1);
  CV(1,  mask_c, 4967552, 1);
  CV(2,  wIn_c,  1769472, 0);
  CV(3,  bIn_c,  2304, 0);
  CV(4,  wOut_c, 589824, 0);
  CV(5,  bOut_c, 768, 0);
  CV(6,  la_c,   49152, 0);
  CV(7,  lb_c,   147456, 0);
  CV(8,  dw_c,   49152, 0);
  CV(9,  db_c,   64, 0);
  CV(10, uw_c,   49152, 0);
  CV(11, ub_c,   768, 0);

  build_wc<<<2304, 256, 0, stream>>>(wIn_c, la_c, lb_c, Wc);

  gemm_bt_8ph<<<99*9, 512, 0, stream>>>(x_c, x_raw, Wc, bIn_c, qkv,
                                        M_TOT, QKV_N, EDIM, 9, flag, 0);
  attn_fused<<<dim3(6144), 256, 0, stream>>>(qkv, mask_c, mask_raw, flag, mz, xop);
  gemm_bt_8ph<<<99*3, 512, 0, stream>>>(xop, xop, wOut_c, bOut_c, d_out,
                                        M_TOT, EDIM, EDIM, 3, flag, 1);
  cls_attn<<<dim3(96), 256, 0, stream>>>(qkv, mask_c, mask_raw, flag, mz, top_idx, Sg, x1b);
  gemm_bt_8ph<<<1*3, 512, 0, stream>>>(x1b, x1b, wOut_c, bOut_c, x1p,
                                       BSZ, EDIM, EDIM, 3, flag, 0);
  final_update<<<128, 256, 0, stream>>>(d_out, x1p, dw_c, db_c, uw_c, ub_c, top_idx, flag);
}

// Round 9
// 561.884 us; speedup vs baseline: 2.0739x; 1.0133x over previous
//
#include <hip/hip_runtime.h>
#include <hip/hip_bf16.h>

typedef __attribute__((ext_vector_type(4))) float f32x4;
typedef __attribute__((ext_vector_type(8))) short s16x8;

#define BSZ 128
#define TGT 197
#define EDIM 768
#define NH 12
#define HD 64
#define NF 16
#define M_TOT (BSZ*TGT)      // 25216
#define QKV_N (3*EDIM)       // 2304
#define KG (NF*TGT)          // 3152
#define KGP 3328
#define VSTR 264

__device__ __forceinline__ float b2f(unsigned short u) {
  return __uint_as_float(((unsigned int)u) << 16);
}
__device__ __forceinline__ float bf2f(__hip_bfloat16 b) { return __bfloat162float(b); }
__device__ __forceinline__ __hip_bfloat16 f2bf(float f) { return __float2bfloat16(f); }
__device__ __forceinline__ unsigned int packbf(float a, float b) {
  __hip_bfloat16 x = __float2bfloat16(a), y = __float2bfloat16(b);
  return (unsigned int)*(unsigned short*)&x | ((unsigned int)*(unsigned short*)&y << 16);
}
__device__ __forceinline__ int swz(int t, int c) {
  return t*64 + (c ^ ((((t & 7) ^ ((t >> 3) & 3))) << 3));
}
__device__ __forceinline__ int vswz(int d, int t) {
  return d*VSTR + (t ^ (d & 56));
}

__device__ __forceinline__ void gload_lds16(const void* gsrc, void* ldst) {
  __builtin_amdgcn_global_load_lds(
      (const __attribute__((address_space(1))) unsigned int*)gsrc,
      (__attribute__((address_space(3))) unsigned int*)ldst, 16, 0, 0);
}

// ---------------- dtype detection (+ init mask-zero flag to 1) ----------------
__global__ void detect_dtype(const unsigned short* __restrict__ xraw,
                             int* __restrict__ flag, int* __restrict__ mz) {
  if (threadIdx.x == 0 && blockIdx.x == 0) {
    float mx = 0.f;
    for (int j = 0; j < 1024; ++j) {
      float v = fabsf(b2f(xraw[j]));
      if (v < 1e30f) mx = fmaxf(mx, v);
      else mx = 1e30f;
    }
    *flag = (mx < 100.0f) ? 1 : 0;
    *mz = 1;
  }
}

// ---------------- mask-zero detection ----------------
__global__ __launch_bounds__(256) void detect_mask_zero(
    const unsigned int* __restrict__ mraw, int nelem,
    const int* __restrict__ flag, int* __restrict__ mz)
{
  const int isbf = *flag;
  const int nwords = isbf ? (nelem >> 1) : nelem;
  const unsigned int am = isbf ? 0x7fff7fffu : 0x7fffffffu;
  unsigned int acc = 0;
  for (int i = blockIdx.x*256 + threadIdx.x; i < nwords; i += gridDim.x*256)
    acc |= (mraw[i] & am);
  if (acc) atomicAnd(mz, 0);
}

// ---------------- canonicalize big float tensor to bf16 (skippable) ----------------
__global__ __launch_bounds__(256) void convert_bf16(
    const void* __restrict__ src, __hip_bfloat16* __restrict__ dst,
    int n8, const int* __restrict__ flag, int skip_if_bf)
{
  const int isbf = *flag;
  if (skip_if_bf && isbf) return;
  int i = blockIdx.x * 256 + threadIdx.x;
  const int stride = gridDim.x * 256;
  if (isbf) {
    const s16x8* s = (const s16x8*)src;
    s16x8* d = (s16x8*)dst;
    for (; i < n8; i += stride) d[i] = s[i];
  } else {
    const f32x4* s = (const f32x4*)src;
    s16x8* d = (s16x8*)dst;
    for (; i < n8; i += stride) {
      f32x4 a = s[i*2], b = s[i*2+1];
      s16x8 o;
      #pragma unroll
      for (int j = 0; j < 4; ++j) { __hip_bfloat16 t = f2bf(a[j]); o[j] = *(short*)&t; }
      #pragma unroll
      for (int j = 0; j < 4; ++j) { __hip_bfloat16 t = f2bf(b[j]); o[4+j] = *(short*)&t; }
      d[i] = o;
    }
  }
}

// ---------------- batched convert for the 10 small weight tensors ----------------
struct CvBatch {
  const void* src[10];
  void* dst[10];
  int off8[11];   // cumulative n8 boundaries
};

__global__ __launch_bounds__(256) void convert_batch(CvBatch cb, const int* __restrict__ flag)
{
  const int isbf = *flag;
  const int total = cb.off8[10];
  for (int i = blockIdx.x*256 + threadIdx.x; i < total; i += gridDim.x*256) {
    int s = 0;
    #pragma unroll
    for (int k = 1; k < 10; ++k) s += (i >= cb.off8[k]);
    const int li = i - cb.off8[s];
    if (isbf) {
      ((s16x8*)cb.dst[s])[li] = ((const s16x8*)cb.src[s])[li];
    } else {
      const f32x4* sp = (const f32x4*)cb.src[s];
      f32x4 a = sp[li*2], b = sp[li*2+1];
      s16x8 o;
      #pragma unroll
      for (int j = 0; j < 4; ++j) { __hip_bfloat16 t = f2bf(a[j]); o[j] = *(short*)&t; }
      #pragma unroll
      for (int j = 0; j < 4; ++j) { __hip_bfloat16 t = f2bf(b[j]); o[4+j] = *(short*)&t; }
      ((s16x8*)cb.dst[s])[li] = o;
    }
  }
}

// ---------------- Wc = in_proj_weight + lora_b @ lora_a ----------------
__global__ __launch_bounds__(256) void build_wc(
    const __hip_bfloat16* __restrict__ W,
    const __hip_bfloat16* __restrict__ la,
    const __hip_bfloat16* __restrict__ lb,
    __hip_bfloat16* __restrict__ Wc)
{
  __shared__ float lbr[64];
  const int n = blockIdx.x;
  if (threadIdx.x < 64) lbr[threadIdx.x] = bf2f(lb[n*64 + threadIdx.x]);
  __syncthreads();
  for (int e = threadIdx.x; e < EDIM; e += 256) {
    float acc = bf2f(W[(size_t)n*EDIM + e]);
    for (int r = 0; r < 64; ++r) acc += lbr[r] * bf2f(la[r*EDIM + e]);
    Wc[(size_t)n*EDIM + e] = f2bf(acc);
  }
}

// ---------------- 256x256 8-phase GEMM, deep-prefetch schedule ----------------
// All 8 of tile t+1's loads issue at phase 0 of tile t; waits: vmcnt(8)@p1
// (guards A1,A3 of t, 5 phases old), vmcnt(2)@p3 (guards t+1's first 6,
// 3 phases old). Tail tiles use vmcnt(0).
__global__ __launch_bounds__(512) void gemm_bt_8ph(
    const __hip_bfloat16* __restrict__ A,
    const __hip_bfloat16* __restrict__ A_alt,
    const __hip_bfloat16* __restrict__ B,
    const __hip_bfloat16* __restrict__ bias,
    void* __restrict__ C,
    int M, int N, int K, int ntiles,
    const int* __restrict__ flag, int flag_mode)
{
  __shared__ char lds[131072];
  const int tid = threadIdx.x;
  const int wave = tid >> 6, lane = tid & 63;
  const int l16 = lane & 15, kq = lane >> 4;
  const int wr = wave >> 2, wc2 = wave & 3;

  const int nwg = gridDim.x;
  const int bid = blockIdx.x;
  const int qc = nwg >> 3, rc = nwg & 7;
  const int xcd = bid & 7;
  const int wgid = (xcd < rc ? xcd*(qc+1) : rc*(qc+1) + (xcd-rc)*qc) + (bid >> 3);
  const long brow = (long)(wgid / ntiles) * 256;
  const long bcol = (long)(wgid % ntiles) * 256;

  const int isbf = *flag;
  const __hip_bfloat16* Ause = isbf ? A_alt : A;
  const int nkt = K >> 6;

  const int srow = tid >> 3;
  const int schunk = tid & 7;
  const int wuni = wave << 10;

  auto stA = [&](int t, int buf, int issue) {
    int ar = issue*64 + srow;
    int cs = schunk ^ (ar & 7);
    long gr = brow + ar; if (gr > (long)M - 1) gr = M - 1;
    gload_lds16(Ause + gr*(long)K + t*64 + cs*8,
                lds + buf*65536 + issue*8192 + wuni);
  };
  auto stB = [&](int t, int buf, int issue) {
    int br = issue*64 + srow;
    int cs = schunk ^ (br & 7);
    gload_lds16(B + (bcol + br)*(long)K + t*64 + cs*8,
                lds + buf*65536 + 32768 + issue*8192 + wuni);
  };
  auto rdA = [&](int buf, int q, int a, int ks) -> s16x8 {
    int ar = wr*128 + q*32 + a*16 + l16;
    int ch = ks*4 + kq;
    return *(const s16x8*)(lds + buf*65536 + ar*128 + ((ch ^ (ar & 7)) << 4));
  };
  auto rdB = [&](int buf, int ni, int ks) -> s16x8 {
    int br = wc2*64 + ni*16 + l16;
    int ch = ks*4 + kq;
    return *(const s16x8*)(lds + buf*65536 + 32768 + br*128 + ((ch ^ (br & 7)) << 4));
  };

  f32x4 acc[8][4];
  #pragma unroll
  for (int i = 0; i < 8; ++i)
    #pragma unroll
    for (int j = 0; j < 4; ++j) acc[i][j] = (f32x4){0.f,0.f,0.f,0.f};

  // prologue: stage tile 0 in consumption order
  stB(0,0,0); stB(0,0,1); stB(0,0,2); stB(0,0,3);
  stA(0,0,0); stA(0,0,2); stA(0,0,1); stA(0,0,3);
  asm volatile("s_waitcnt vmcnt(2)" ::: "memory");
  __builtin_amdgcn_s_barrier();

  for (int t = 0; t < nkt; ++t) {
    const int cur = t & 1, nxt = cur ^ 1;
    const bool pf = (t + 1 < nkt);
    s16x8 bfr[4][2], af[2][2];

    // ---- phase 0: B frags + A q0; issue ALL 8 prefetches for t+1 ----
    #pragma unroll
    for (int ni = 0; ni < 4; ++ni) { bfr[ni][0] = rdB(cur,ni,0); bfr[ni][1] = rdB(cur,ni,1); }
    af[0][0]=rdA(cur,0,0,0); af[0][1]=rdA(cur,0,0,1);
    af[1][0]=rdA(cur,0,1,0); af[1][1]=rdA(cur,0,1,1);
    if (pf) {
      stB(t+1,nxt,0); stB(t+1,nxt,1); stB(t+1,nxt,2); stB(t+1,nxt,3);
      stA(t+1,nxt,0); stA(t+1,nxt,2); stA(t+1,nxt,1); stA(t+1,nxt,3);
    }
    __builtin_amdgcn_s_barrier();
    asm volatile("s_waitcnt lgkmcnt(0)" ::: "memory");
    __builtin_amdgcn_sched_barrier(0);
    __builtin_amdgcn_s_setprio(1);
    #pragma unroll
    for (int ks = 0; ks < 2; ++ks)
      #pragma unroll
      for (int ni = 0; ni < 4; ++ni) {
        acc[0][ni] = __builtin_amdgcn_mfma_f32_16x16x32_bf16(af[0][ks], bfr[ni][ks], acc[0][ni], 0,0,0);
        acc[1][ni] = __builtin_amdgcn_mfma_f32_16x16x32_bf16(af[1][ks], bfr[ni][ks], acc[1][ni], 0,0,0);
      }
    __builtin_amdgcn_s_setprio(0);

    // ---- phase 1: A q1; vmcnt(8) guards A1,A3(cur) for phases 2-3 ----
    af[0][0]=rdA(cur,1,0,0); af[0][1]=rdA(cur,1,0,1);
    af[1][0]=rdA(cur,1,1,0); af[1][1]=rdA(cur,1,1,1);
    if (pf) asm volatile("s_waitcnt vmcnt(8)" ::: "memory");
    else    asm volatile("s_waitcnt vmcnt(0)" ::: "memory");
    __builtin_amdgcn_s_barrier();
    asm volatile("s_waitcnt lgkmcnt(0)" ::: "memory");
    __builtin_amdgcn_sched_barrier(0);
    __builtin_amdgcn_s_setprio(1);
    #pragma unroll
    for (int ks = 0; ks < 2; ++ks)
      #pragma unroll
      for (int ni = 0; ni < 4; ++ni) {
        acc[2][ni] = __builtin_amdgcn_mfma_f32_16x16x32_bf16(af[0][ks], bfr[ni][ks], acc[2][ni], 0,0,0);
        acc[3][ni] = __builtin_amdgcn_mfma_f32_16x16x32_bf16(af[1][ks], bfr[ni][ks], acc[3][ni], 0,0,0);
      }
    __builtin_amdgcn_s_setprio(0);

    // ---- phase 2: A q2 ----
    af[0][0]=rdA(cur,2,0,0); af[0][1]=rdA(cur,2,0,1);
    af[1][0]=rdA(cur,2,1,0); af[1][1]=rdA(cur,2,1,1);
    __builtin_amdgcn_s_barrier();
    asm volatile("s_waitcnt lgkmcnt(0)" ::: "memory");
    __builtin_amdgcn_sched_barrier(0);
    __builtin_amdgcn_s_setprio(1);
    #pragma unroll
    for (int ks = 0; ks < 2; ++ks)
      #pragma unroll
      for (int ni = 0; ni < 4; ++ni) {
        acc[4][ni] = __builtin_amdgcn_mfma_f32_16x16x32_bf16(af[0][ks], bfr[ni][ks], acc[4][ni], 0,0,0);
        acc[5][ni] = __builtin_amdgcn_mfma_f32_16x16x32_bf16(af[1][ks], bfr[ni][ks], acc[5][ni], 0,0,0);
      }
    __builtin_amdgcn_s_setprio(0);

    // ---- phase 3: A q3; vmcnt(2) guards t+1's B + A0,A2 (3 phases old) ----
    af[0][0]=rdA(cur,3,0,0); af[0][1]=rdA(cur,3,0,1);
    af[1][0]=rdA(cur,3,1,0); af[1][1]=rdA(cur,3,1,1);
    if (pf) asm volatile("s_waitcnt vmcnt(2)" ::: "memory");
    __builtin_amdgcn_s_barrier();
    asm volatile("s_waitcnt lgkmcnt(0)" ::: "memory");
    __builtin_amdgcn_sched_barrier(0);
    __builtin_amdgcn_s_setprio(1);
    #pragma unroll
    for (int ks = 0; ks < 2; ++ks)
      #pragma unroll
      for (int ni = 0; ni < 4; ++ni) {
        acc[6][ni] = __builtin_amdgcn_mfma_f32_16x16x32_bf16(af[0][ks], bfr[ni][ks], acc[6][ni], 0,0,0);
        acc[7][ni] = __builtin_amdgcn_mfma_f32_16x16x32_bf16(af[1][ks], bfr[ni][ks], acc[7][ni], 0,0,0);
      }
    __builtin_amdgcn_s_setprio(0);
  }

  __builtin_amdgcn_s_barrier();

  const int f32o = flag_mode && (!isbf);
  float bv[4];
  #pragma unroll
  for (int ni = 0; ni < 4; ++ni) bv[ni] = bf2f(bias[bcol + wc2*64 + ni*16 + l16]);
  const int o4 = kq*4;

  if (!f32o) {
    __hip_bfloat16* eb = (__hip_bfloat16*)(lds + wave*2048);
    __hip_bfloat16* Cb = (__hip_bfloat16*)C;
    const int rr = lane >> 3, cg = lane & 7;
    #pragma unroll
    for (int mi = 0; mi < 8; ++mi) {
      #pragma unroll
      for (int ni = 0; ni < 4; ++ni)
        #pragma unroll
        for (int r = 0; r < 4; ++r) {
          const int row16 = o4 + r;
          const int sidx = row16*64 + ((((ni*2 + (l16 >> 3)) ^ (row16 & 7)) << 3) | (l16 & 7));
          eb[sidx] = f2bf(acc[mi][ni][r] + bv[ni]);
        }
      asm volatile("s_waitcnt lgkmcnt(0)" ::: "memory");
      __builtin_amdgcn_sched_barrier(0);
      #pragma unroll
      for (int pass = 0; pass < 2; ++pass) {
        const int row16 = pass*8 + rr;
        const long grow = brow + wr*128 + mi*16 + row16;
        if (grow < M) {
          s16x8 v = *(const s16x8*)(eb + row16*64 + ((cg ^ (row16 & 7)) << 3));
          *(s16x8*)(Cb + grow*(long)N + bcol + wc2*64 + cg*8) = v;
        }
      }
      asm volatile("s_waitcnt lgkmcnt(0)" ::: "memory");
      __builtin_amdgcn_sched_barrier(0);
    }
  } else {
    #pragma unroll
    for (int mi = 0; mi < 8; ++mi)
      #pragma unroll
      for (int ni = 0; ni < 4; ++ni)
        #pragma unroll
        for (int r = 0; r < 4; ++r) {
          const long grow = brow + wr*128 + mi*16 + o4 + r;
          if (grow < M)
            ((float*)C)[grow*(long)N + bcol + wc2*64 + ni*16 + l16] = acc[mi][ni][r] + bv[ni];
        }
  }
}

// ---------------- fused attention: V^T-only LDS, K direct from global ----------------
__global__ __launch_bounds__(256) void attn_fused(
    const __hip_bfloat16* __restrict__ qkv,
    const __hip_bfloat16* __restrict__ mask,
    const __hip_bfloat16* __restrict__ mask_raw,
    const int* __restrict__ flag,
    const int* __restrict__ mzp,
    __hip_bfloat16* __restrict__ xop)
{
  __shared__ __hip_bfloat16 lVt[64*VSTR];

  const int tid = threadIdx.x;
  const int blk = blockIdx.x;
  const int xcd = blk & 7;
  const int slot = blk >> 3;
  const int ih = xcd * 192 + (slot >> 2);
  const int qt = slot & 3;
  const int h = ih % NH;
  const int i = ih / NH;
  const int q0 = qt * 64;
  const size_t rowbase = (size_t)i * TGT;
  const int wave = tid >> 6, lane = tid & 63;
  const int l16 = lane & 15, kq = lane >> 4;
  const int mz = *mzp;
  const __hip_bfloat16* msk = (*flag) ? mask_raw : mask;

  int qr = q0 + wave*16 + l16;
  const int qrc = qr > TGT-1 ? TGT-1 : qr;
  s16x8 qf[2];
  #pragma unroll
  for (int kk = 0; kk < 2; ++kk)
    qf[kk] = *(const s16x8*)(qkv + (rowbase + qrc)*QKV_N + h*HD + kk*32 + kq*8);

  const f32x4 z = {0.f,0.f,0.f,0.f};
  for (int idx = tid; idx < 224*8; idx += 256) {
    int t = idx >> 3, c8 = idx & 7;
    f32x4 vv = z;
    if (t < TGT) vv = *(const f32x4*)(qkv + (rowbase + t)*QKV_N + 2*EDIM + h*HD + c8*8);
    const __hip_bfloat16* pv = (const __hip_bfloat16*)&vv;
    const int tx = t ^ (c8 << 3);
    #pragma unroll
    for (int j = 0; j < 8; ++j)
      lVt[(c8*8 + j)*VSTR + tx] = pv[j];
  }
  __syncthreads();

  f32x4 acc[14];
  #pragma unroll
  for (int nf = 0; nf < 14; ++nf) {
    int trow = nf*16 + l16; if (trow > TGT-1) trow = TGT-1;
    acc[nf] = (f32x4){0.f,0.f,0.f,0.f};
    #pragma unroll
    for (int kk = 0; kk < 2; ++kk) {
      s16x8 kf = *(const s16x8*)(qkv + (rowbase + trow)*QKV_N + EDIM + h*HD + kk*32 + kq*8);
      acc[nf] = __builtin_amdgcn_mfma_f32_16x16x32_bf16(kf, qf[kk], acc[nf], 0, 0, 0);
    }
  }

  float mx = -1e30f;
  #pragma unroll
  for (int nf = 0; nf < 14; ++nf) {
    #pragma unroll
    for (int r = 0; r < 4; ++r) {
      const int t = nf*16 + kq*4 + r;
      float s;
      if (t < TGT) {
        s = acc[nf][r]*0.125f;
        if (!mz) s += bf2f(msk[(rowbase + qrc)*TGT + t]);
      } else s = -1e30f;
      acc[nf][r] = s;
      mx = fmaxf(mx, s);
    }
  }
  mx = fmaxf(mx, __shfl_xor(mx, 16));
  mx = fmaxf(mx, __shfl_xor(mx, 32));

  float rs = 0.f;
  unsigned int pk[14][2];
  #pragma unroll
  for (int nf = 0; nf < 14; ++nf) {
    float p0 = __expf(acc[nf][0] - mx);
    float p1 = __expf(acc[nf][1] - mx);
    float p2 = __expf(acc[nf][2] - mx);
    float p3 = __expf(acc[nf][3] - mx);
    rs += (p0 + p1) + (p2 + p3);
    pk[nf][0] = packbf(p0, p1);
    pk[nf][1] = packbf(p2, p3);
  }
  rs += __shfl_xor(rs, 16);
  rs += __shfl_xor(rs, 32);

  f32x4 oacc[4];
  #pragma unroll
  for (int nf = 0; nf < 4; ++nf) oacc[nf] = (f32x4){0.f,0.f,0.f,0.f};

  const int slbase = l16 + ((kq & 1) << 5);
  #pragma unroll
  for (int kt = 0; kt < 7; ++kt) {
    s16x8 pa;
    #pragma unroll
    for (int jp = 0; jp < 4; ++jp) {
      const int srcLane = slbase + ((jp >> 1) << 4);
      int va = __shfl((int)pk[2*kt][jp & 1], srcLane, 64);
      int vb = __shfl((int)pk[2*kt + 1][jp & 1], srcLane, 64);
      int sel = (kq < 2) ? va : vb;
      pa[2*jp]     = (short)(sel & 0xffff);
      pa[2*jp + 1] = (short)(((unsigned int)sel) >> 16);
    }
    #pragma unroll
    for (int nf = 0; nf < 4; ++nf) {
      s16x8 vf = *(const s16x8*)(lVt + vswz(nf*16 + l16, kt*32 + kq*8));
      oacc[nf] = __builtin_amdgcn_mfma_f32_16x16x32_bf16(pa, vf, oacc[nf], 0, 0, 0);
    }
  }

  #pragma unroll
  for (int r = 0; r < 4; ++r) {
    const float rsrc = __shfl(rs, kq*4 + r, 64);
    const int qw = q0 + wave*16 + kq*4 + r;
    if (qw < TGT) {
      const float inv = 1.0f / rsrc;
      #pragma unroll
      for (int nf = 0; nf < 4; ++nf)
        xop[(rowbase + qw)*(size_t)EDIM + h*HD + nf*16 + l16] = f2bf(oacc[nf][r] * inv);
    }
  }
}

// ---------------- CLS grouped attention ----------------
__global__ __launch_bounds__(256) void cls_attn(
    const __hip_bfloat16* __restrict__ qkv,
    const __hip_bfloat16* __restrict__ mask,
    const __hip_bfloat16* __restrict__ mask_raw,
    const int* __restrict__ flag,
    const int* __restrict__ mzp,
    const int* __restrict__ top_idx,
    __hip_bfloat16* __restrict__ Sg_all,
    __hip_bfloat16* __restrict__ x1buf)
{
  __shared__ __hip_bfloat16 lQ[16*64];
  __shared__ __hip_bfloat16 lV[256*64];
  __shared__ float red[16][17];
  __shared__ float rmax[16];
  __shared__ float rsum[16];

  const int tid = threadIdx.x;
  const int g = blockIdx.x / NH;
  const int h = blockIdx.x % NH;
  __hip_bfloat16* Sg = Sg_all + (size_t)blockIdx.x * 16 * KGP;
  const int wave = tid >> 6, lane = tid & 63;
  const int l16 = lane & 15, kq = lane >> 4, o4 = (lane >> 4) * 4;
  const int mz = *mzp;
  const __hip_bfloat16* msk = (*flag) ? mask_raw : mask;

  if (tid < 128) {
    int qi = tid >> 3, c8 = tid & 7;
    int ib = g*NF + qi;
    int top = top_idx[ib];
    f32x4 v = *(const f32x4*)(qkv + ((size_t)ib*TGT + top)*QKV_N + h*HD + c8*8);
    *(f32x4*)(lQ + qi*64 + c8*8) = v;
  }
  __syncthreads();

  s16x8 q8[2];
  #pragma unroll
  for (int kk = 0; kk < 2; ++kk)
    q8[kk] = *(const s16x8*)(lQ + l16*64 + kk*32 + kq*8);

  for (int nf = wave; nf < 208; nf += 4) {
    const int key = nf*16 + l16;
    if (nf < 197) {
      f32x4 a = {0.f,0.f,0.f,0.f};
      const size_t krow = (size_t)g*KG + key;
      #pragma unroll
      for (int kk = 0; kk < 2; ++kk) {
        s16x8 k8 = *(const s16x8*)(qkv + krow*QKV_N + EDIM + h*HD + kk*32 + kq*8);
        a = __builtin_amdgcn_mfma_f32_16x16x32_bf16(q8[kk], k8, a, 0, 0, 0);
      }
      float mval = 0.f;
      if (!mz) {
        const int f = key / 197;
        const int t = key - f*197;
        mval = bf2f(msk[((size_t)(g*NF + f)*TGT + (TGT-1))*TGT + t]);
      }
      #pragma unroll
      for (int r = 0; r < 4; ++r)
        Sg[(o4 + r)*KGP + key] = f2bf(a[r]*0.125f + mval);
    } else {
      #pragma unroll
      for (int r = 0; r < 4; ++r)
        Sg[(o4 + r)*KGP + key] = f2bf(0.f);
    }
  }
  __syncthreads();

  {
    const int q = tid >> 4, c = tid & 15;
    float mx = -1e30f;
    for (int gch = c; gch < 394; gch += 16) {
      s16x8 sv = *(const s16x8*)(Sg + q*KGP + gch*8);
      #pragma unroll
      for (int j = 0; j < 8; ++j) mx = fmaxf(mx, b2f((unsigned short)sv[j]));
    }
    red[q][c] = mx;
    __syncthreads();
    if (tid < 16) {
      float m = red[tid][0];
      for (int j = 1; j < 16; ++j) m = fmaxf(m, red[tid][j]);
      rmax[tid] = m;
    }
    __syncthreads();
    const float rowmax = rmax[q];
    float sum = 0.f;
    for (int gch = c; gch < 394; gch += 16) {
      s16x8 sv = *(const s16x8*)(Sg + q*KGP + gch*8);
      s16x8 ov;
      #pragma unroll
      for (int jp = 0; jp < 4; ++jp) {
        float e0 = __expf(b2f((unsigned short)sv[2*jp])   - rowmax);
        float e1 = __expf(b2f((unsigned short)sv[2*jp+1]) - rowmax);
        sum += e0 + e1;
        unsigned int pr = packbf(e0, e1);
        ov[2*jp]   = (short)(pr & 0xffff);
        ov[2*jp+1] = (short)(pr >> 16);
      }
      *(s16x8*)(Sg + q*KGP + gch*8) = ov;
    }
    red[q][c] = sum;
    __syncthreads();
    if (tid < 16) {
      float s = 0.f;
      for (int j = 0; j < 16; ++j) s += red[tid][j];
      rsum[tid] = s;
    }
  }

  f32x4 oa = {0.f,0.f,0.f,0.f};
  const f32x4 z = {0.f,0.f,0.f,0.f};
  for (int ck = 0; ck < KGP; ck += 256) {
    __syncthreads();
    for (int idx = tid; idx < 256*8; idx += 256) {
      int t2 = idx >> 3, c8 = idx & 7;
      int key = ck + t2;
      f32x4 v = z;
      if (key < KG) v = *(const f32x4*)(qkv + ((size_t)g*KG + key)*QKV_N + 2*EDIM + h*HD + c8*8);
      *(f32x4*)(lV + swz(t2, c8*8)) = v;
    }
    __syncthreads();
    #pragma unroll
    for (int ks = 0; ks < 8; ++ks) {
      s16x8 pa = *(const s16x8*)(Sg + l16*KGP + ck + ks*32 + kq*8);
      s16x8 vf;
      #pragma unroll
      for (int j = 0; j < 8; ++j) {
        const int t2 = ks*32 + kq*8 + j;
        vf[j] = *(const short*)(lV + swz(t2, wave*16 + l16));
      }
      oa = __builtin_amdgcn_mfma_f32_16x16x32_bf16(pa, vf, oa, 0, 0, 0);
    }
  }
  #pragma unroll
  for (int r = 0; r < 4; ++r) {
    int q = o4 + r;
    int ib = g*NF + q;
    x1buf[(size_t)ib*EDIM + h*HD + wave*16 + l16] = f2bf(oa[r] / rsum[q]);
  }
}

// ---------------- LoRA head + CLS row update ----------------
__global__ __launch_bounds__(256) void final_update(
    void* __restrict__ out,
    const __hip_bfloat16* __restrict__ x1p,
    const __hip_bfloat16* __restrict__ dw, const __hip_bfloat16* __restrict__ db,
    const __hip_bfloat16* __restrict__ uw, const __hip_bfloat16* __restrict__ ub,
    const int* __restrict__ top_idx, const int* __restrict__ flag)
{
  __shared__ float x0[EDIM];
  __shared__ float hmid[64];
  const int i = blockIdx.x;
  const int tid = threadIdx.x;
  const int top = top_idx[i];
  const int isbf = *flag;
  const size_t rowoff = ((size_t)i*TGT + top)*EDIM;
  for (int e = tid; e < EDIM; e += 256)
    x0[e] = isbf ? bf2f(((const __hip_bfloat16*)out)[rowoff + e])
                 : ((const float*)out)[rowoff + e];
  __syncthreads();
  if (tid < 64) {
    float a = bf2f(db[tid]);
    for (int e = 0; e < EDIM; ++e) a += x0[e] * bf2f(dw[tid*EDIM + e]);
    hmid[tid] = a / (1.f + __expf(-1.702f * a));
  }
  __syncthreads();
  for (int e = tid; e < EDIM; e += 256) {
    float a = bf2f(ub[e]) + bf2f(x1p[(size_t)i*EDIM + e]);
    #pragma unroll
    for (int r = 0; r < 64; ++r) a += hmid[r] * bf2f(uw[e*64 + r]);
    if (isbf) ((__hip_bfloat16*)out)[rowoff + e] = f2bf(a);
    else ((float*)out)[rowoff + e] = a;
  }
}

extern "C" void kernel_launch(void* const* d_in, const int* in_sizes, int n_in,
                              void* d_out, int out_size, void* d_ws, size_t ws_size,
                              hipStream_t stream) {
  (void)in_sizes; (void)n_in; (void)out_size; (void)ws_size;
  const int* top_idx = (const int*)d_in[13];
  const __hip_bfloat16* x_raw    = (const __hip_bfloat16*)d_in[0];
  const __hip_bfloat16* mask_raw = (const __hip_bfloat16*)d_in[1];

  char* ws = (char*)d_ws;
  size_t off = 0;
  auto alloc = [&](size_t bytes) { char* p = ws + off; off += (bytes + 15) & ~(size_t)15; return p; };

  int* flag = (int*)alloc(16);
  int* mz   = (int*)alloc(16);
  __hip_bfloat16* x_c    = (__hip_bfloat16*)alloc((size_t)19365888*2);
  __hip_bfloat16* mask_c = (__hip_bfloat16*)alloc((size_t)4967552*2);
  __hip_bfloat16* wIn_c  = (__hip_bfloat16*)alloc((size_t)1769472*2);
  __hip_bfloat16* bIn_c  = (__hip_bfloat16*)alloc((size_t)2304*2);
  __hip_bfloat16* wOut_c = (__hip_bfloat16*)alloc((size_t)589824*2);
  __hip_bfloat16* bOut_c = (__hip_bfloat16*)alloc((size_t)768*2);
  __hip_bfloat16* la_c   = (__hip_bfloat16*)alloc((size_t)49152*2);
  __hip_bfloat16* lb_c   = (__hip_bfloat16*)alloc((size_t)147456*2);
  __hip_bfloat16* dw_c   = (__hip_bfloat16*)alloc((size_t)49152*2);
  __hip_bfloat16* db_c   = (__hip_bfloat16*)alloc((size_t)64*2);
  __hip_bfloat16* uw_c   = (__hip_bfloat16*)alloc((size_t)49152*2);
  __hip_bfloat16* ub_c   = (__hip_bfloat16*)alloc((size_t)768*2);
  __hip_bfloat16* Wc     = (__hip_bfloat16*)alloc((size_t)QKV_N*EDIM*2);
  __hip_bfloat16* qkv    = (__hip_bfloat16*)alloc((size_t)M_TOT*QKV_N*2);
  __hip_bfloat16* xop    = (__hip_bfloat16*)alloc((size_t)M_TOT*EDIM*2);
  __hip_bfloat16* x1b    = (__hip_bfloat16*)alloc((size_t)BSZ*EDIM*2);
  __hip_bfloat16* x1p    = (__hip_bfloat16*)alloc((size_t)BSZ*EDIM*2);
  __hip_bfloat16* Sg     = (__hip_bfloat16*)alloc((size_t)96*16*KGP*2);

  detect_dtype<<<1, 64, 0, stream>>>((const unsigned short*)d_in[0], flag, mz);
  detect_mask_zero<<<2048, 256, 0, stream>>>((const unsigned int*)d_in[1], 4967552, flag, mz);

  // big tensors: skip-if-bf16 converts
  convert_bf16<<<2048, 256, 0, stream>>>(d_in[0], x_c, 19365888/8, flag, 1);
  convert_bf16<<<2048, 256, 0, stream>>>(d_in[1], mask_c, 4967552/8, flag, 1);

  // 10 small weight tensors: one batched convert
  CvBatch cb;
  const int srcIdx[10] = {2,3,4,5,6,7,8,9,10,11};
  void* dsts[10] = {wIn_c, bIn_c, wOut_c, bOut_c, la_c, lb_c, dw_c, db_c, uw_c, ub_c};
  const int ns[10] = {1769472, 2304, 589824, 768, 49152, 147456, 49152, 64, 49152, 768};
  int cum = 0;
  for (int k = 0; k < 10; ++k) {
    cb.src[k] = d_in[srcIdx[k]];
    cb.dst[k] = dsts[k];
    cb.off8[k] = cum;
    cum += ns[k] / 8;
  }
  cb.off8[10] = cum;   // 332264
  convert_batch<<<(cum + 255)/256, 256, 0, stream>>>(cb, flag);

  build_wc<<<2304, 256, 0, stream>>>(wIn_c, la_c, lb_c, Wc);

  gemm_bt_8ph<<<99*9, 512, 0, stream>>>(x_c, x_raw, Wc, bIn_c, qkv,
                                        M_TOT, QKV_N, EDIM, 9, flag, 0);
  attn_fused<<<dim3(6144), 256, 0, stream>>>(qkv, mask_c, mask_raw, flag, mz, xop);
  gemm_bt_8ph<<<99*3, 512, 0, stream>>>(xop, xop, wOut_c, bOut_c, d_out,
                                        M_TOT, EDIM, EDIM, 3, flag, 1);
  cls_attn<<<dim3(96), 256, 0, stream>>>(qkv, mask_c, mask_raw, flag, mz, top_idx, Sg, x1b);
  gemm_bt_8ph<<<1*3, 512, 0, stream>>>(x1b, x1b, wOut_c, bOut_c, x1p,
                                       BSZ, EDIM, EDIM, 3, flag, 0);
  final_update<<<128, 256, 0, stream>>>(d_out, x1p, dw_c, db_c, uw_c, ub_c, top_idx, flag);
}